// Round 18
// baseline (206.504 us; speedup 1.0000x reference)
//
#include <hip/hip_runtime.h>
#include <hip/hip_fp16.h>
#include <cstdint>
#include <cstddef>
#include <cmath>

// ---------------------------------------------------------------------------
// GCN via CSR aggregation:
//   k_prep: cursor init + precompute W1/W2/Wf MFMA fragments (fp16 frag arrays)
//   binning: fixed-capacity dst-buckets (64 nodes, CAP=3072) -> k_pass1
//            packs edges into tmp runs -> k_p2x: 2-copy LDS histogram ->
//            wave-0 shfl scan -> rcp/dinv -> 2-copy cursor scatter -> fused
//            xform1 MFMA tail (1 tile/wave) for its 64 nodes.
//   agg: one wave per node, 4 lane-groups of 16, fp8 rows; unroll-8,
//        wave-uniform main loop (packed f32x2 adds) + single predicated tail.
//   xform2/final: MFMA 16x16x32 f16 persistent blocks, fp8 pack/unpack via
//   v_cvt_pk_fp8_f32 / v_cvt_pk_f32_fp8 (byte b of uint s = channel s+16b).
//   tmp aliases B2 (dead before first k_agg write).
// ---------------------------------------------------------------------------

#define T1  4096    // edges per pass-1 tile
#define BSH 6       // 64-node buckets
#define CAP 3072    // bucket capacity (avg 2046, sigma ~45)

typedef _Float16 half8 __attribute__((ext_vector_type(8)));
typedef float f32x4 __attribute__((ext_vector_type(4)));
typedef float f32x2 __attribute__((ext_vector_type(2)));

// cursor init + weight-fragment precompute (one block)
__global__ __launch_bounds__(1024) void k_prep(const float* __restrict__ W1,
        const float* __restrict__ W2, const float* __restrict__ Wf,
        int* __restrict__ cursor1, uint4* __restrict__ W1fr,
        uint4* __restrict__ W2fr, uint4* __restrict__ Wffr, int NB) {
    int t = threadIdx.x;
    for (int i = t; i < NB; i += 1024) cursor1[i] = i * CAP;
    if (t < 64) {
        int r16 = t & 15, kg = t >> 4;
        #pragma unroll
        for (int ct = 0; ct < 4; ++ct)
            #pragma unroll
            for (int kt = 0; kt < 4; ++kt) {
                half8 h;
                #pragma unroll
                for (int j = 0; j < 8; ++j)
                    h[j] = (_Float16)W1[(kt * 32 + kg * 8 + j) * 64 + ct * 16 + r16];
                W1fr[(ct * 4 + kt) * 64 + t] = *(uint4*)&h;
            }
        #pragma unroll
        for (int ct = 0; ct < 4; ++ct)
            #pragma unroll
            for (int kt = 0; kt < 2; ++kt) {
                half8 h;
                #pragma unroll
                for (int j = 0; j < 8; ++j)
                    h[j] = (_Float16)W2[(kt * 32 + kg * 8 + j) * 64 + ct * 16 + r16];
                W2fr[(ct * 2 + kt) * 64 + t] = *(uint4*)&h;
            }
        #pragma unroll
        for (int ct = 0; ct < 3; ++ct)
            #pragma unroll
            for (int kt = 0; kt < 2; ++kt) {
                int col = ct * 16 + r16;
                half8 h;
                #pragma unroll
                for (int j = 0; j < 8; ++j)
                    h[j] = (col < 40) ? (_Float16)Wf[(kt * 32 + kg * 8 + j) * 40 + col]
                                      : (_Float16)0.f;
                Wffr[(ct * 2 + kt) * 64 + t] = *(uint4*)&h;
            }
    }
}

__global__ __launch_bounds__(256) void k_pass1(const int* __restrict__ src,
        const int* __restrict__ dst, int* __restrict__ cursor1,
        unsigned int* __restrict__ tmp, int E, int NB) {
    __shared__ unsigned int pack[T1];                 // 16 KB
    __shared__ unsigned short bkt[T1];                //  8 KB
    __shared__ int h[2048], hs_[2048], gbase[2048];   // 24 KB
    int t = threadIdx.x;
    for (int i = t; i < 2048; i += 256) h[i] = 0;
    __syncthreads();
    int base = blockIdx.x * T1;
    int n = min(T1, E - base);
    unsigned int pk[16];
    int bl[16];
    #pragma unroll
    for (int i = 0; i < 16; ++i) {
        int idx = i * 256 + t;
        if (idx < n) {
            int s_ = src[base + idx], d = dst[base + idx];
            int b = d >> BSH;
            pk[i] = (unsigned int)s_ | ((unsigned int)(d & 63) << 17);
            int lo = atomicAdd(&h[b], 1);
            bl[i] = (b << 13) | lo;
        } else bl[i] = -1;
    }
    __syncthreads();
    #pragma unroll
    for (int i = 0; i < 8; ++i) hs_[t + i * 256] = h[t + i * 256];
    __syncthreads();
    for (int st = 1; st < 2048; st <<= 1) {
        int tp[8];
        #pragma unroll
        for (int i = 0; i < 8; ++i) {
            int idx = t + i * 256;
            tp[i] = (idx >= st) ? hs_[idx - st] : 0;
        }
        __syncthreads();
        #pragma unroll
        for (int i = 0; i < 8; ++i) hs_[t + i * 256] += tp[i];
        __syncthreads();
    }
    for (int i = t; i < NB; i += 256)
        gbase[i] = h[i] ? atomicAdd(&cursor1[i], h[i]) : 0;
    __syncthreads();
    #pragma unroll
    for (int i = 0; i < 16; ++i) {
        if (bl[i] >= 0) {
            int b = bl[i] >> 13, lo = bl[i] & 8191;
            int slot = hs_[b] - h[b] + lo;
            pack[slot] = pk[i];
            bkt[slot]  = (unsigned short)b;
        }
    }
    __syncthreads();
    for (int s_ = t; s_ < n; s_ += 256) {
        int b = bkt[s_];
        tmp[gbase[b] + (s_ - (hs_[b] - h[b]))] = pack[s_];
    }
}

// per-bucket (64 nodes): 2-copy histogram -> wave-0 shfl scan -> rcp/dinv ->
// 2-copy cursor scatter -> fused xform1 MFMA tail (1 tile per wave).
__global__ __launch_bounds__(256) void k_p2x(const unsigned int* __restrict__ tmp,
        const int* __restrict__ cursor1, int2* __restrict__ rcp,
        int* __restrict__ csrc, float* __restrict__ dinv,
        const float* __restrict__ x, const uint4* __restrict__ W1fr,
        unsigned int* __restrict__ hs, int N) {
    __shared__ int c[2][64], cur[2][64];
    __shared__ float sdinv[64];
    int t = threadIdx.x, b = blockIdx.x;
    if (t < 128) c[t >> 6][t & 63] = 0;
    __syncthreads();
    int s0 = b * CAP, s1 = cursor1[b];
    int half = t >> 7;
    for (int s = s0 + t; s < s1; s += 256)
        atomicAdd(&c[half][(tmp[s] >> 17) & 63], 1);
    __syncthreads();
    if (t < 64) {
        int c0 = c[0][t];
        int tot = c0 + c[1][t];
        int v = tot;                     // inclusive scan over 64 lanes
        #pragma unroll
        for (int o = 1; o < 64; o <<= 1) {
            int u = __shfl_up(v, o, 64);
            if (t >= o) v += u;
        }
        int rp = s0 + v - tot;           // exclusive prefix
        int node = b * 64 + t;
        float dv = rsqrtf((float)tot + 1.0f);   // +1 self loop
        sdinv[t] = dv;
        if (node < N) {
            rcp[node]  = make_int2(rp, tot);
            dinv[node] = dv;
        }
        cur[0][t] = rp;
        cur[1][t] = rp + c0;
    }
    __syncthreads();
    for (int s = s0 + t; s < s1; s += 256) {
        unsigned int p = tmp[s];
        int q = atomicAdd(&cur[half][(p >> 17) & 63], 1);
        csrc[q] = (int)(p & 0x1FFFFu);
    }
    __syncthreads();
    // ---------------- fused xform1 MFMA tail (64 nodes, 1 tile/wave) ------
    int lane = t & 63, wid = t >> 6;
    int r16 = lane & 15, kg = lane >> 4;
    half8 bf[4][4];                       // [coltile][ktile]
    #pragma unroll
    for (int ct = 0; ct < 4; ++ct)
        #pragma unroll
        for (int kt = 0; kt < 4; ++kt)
            bf[ct][kt] = *(const half8*)&W1fr[(ct * 4 + kt) * 64 + lane];
    int v0 = b * 64 + wid * 16;
    int rowA = min(v0 + r16, N - 1);
    const float* xp = x + (size_t)rowA * 128 + kg * 8;
    half8 af[4];
    #pragma unroll
    for (int kt = 0; kt < 4; ++kt) {
        float4 p = *(const float4*)(xp + kt * 32);
        float4 q = *(const float4*)(xp + kt * 32 + 4);
        half8 a;
        a[0] = (_Float16)p.x; a[1] = (_Float16)p.y;
        a[2] = (_Float16)p.z; a[3] = (_Float16)p.w;
        a[4] = (_Float16)q.x; a[5] = (_Float16)q.y;
        a[6] = (_Float16)q.z; a[7] = (_Float16)q.w;
        af[kt] = a;
    }
    f32x4 acc0 = {0,0,0,0}, acc1 = {0,0,0,0}, acc2 = {0,0,0,0}, acc3 = {0,0,0,0};
    #pragma unroll
    for (int kt = 0; kt < 4; ++kt) {
        acc0 = __builtin_amdgcn_mfma_f32_16x16x32_f16(af[kt], bf[0][kt], acc0, 0, 0, 0);
        acc1 = __builtin_amdgcn_mfma_f32_16x16x32_f16(af[kt], bf[1][kt], acc1, 0, 0, 0);
        acc2 = __builtin_amdgcn_mfma_f32_16x16x32_f16(af[kt], bf[2][kt], acc2, 0, 0, 0);
        acc3 = __builtin_amdgcn_mfma_f32_16x16x32_f16(af[kt], bf[3][kt], acc3, 0, 0, 0);
    }
    #pragma unroll
    for (int r = 0; r < 4; ++r) {
        int nd = v0 + kg * 4 + r;
        if (nd < N) {
            float d = sdinv[wid * 16 + kg * 4 + r];
            int pk = __builtin_amdgcn_cvt_pk_fp8_f32(d * acc0[r], d * acc1[r], 0, false);
            pk     = __builtin_amdgcn_cvt_pk_fp8_f32(d * acc2[r], d * acc3[r], pk, true);
            hs[((size_t)nd << 4) + r16] = (unsigned int)pk;
        }
    }
}

// --- one wave per node, 4 lane-groups of 16; uniform main + masked tail ----
// fp8 row = 16 uints; byte b of uint s = channel s + 16*b.
__global__ __launch_bounds__(256) void k_agg(const int2* __restrict__ rcp,
        const int* __restrict__ csrc, const unsigned int* __restrict__ hp,
        float* __restrict__ acc, int N) {
    int w = (blockIdx.x * 256 + threadIdx.x) >> 6;
    int lane = threadIdx.x & 63;
    if (w >= N) return;
    int grp = lane >> 4, sub = lane & 15;
    int2 rc = rcp[w];
    int rs = rc.x, re = rc.x + rc.y;
    f32x2 A = {0.f, 0.f}, B = {0.f, 0.f};   // {sub, sub+16}, {sub+32, sub+48}
    if (grp == 0) {                                     // self loop, once
        unsigned v = hp[((size_t)w << 4) + sub];
        A = __builtin_amdgcn_cvt_pk_f32_fp8((int)v, false);
        B = __builtin_amdgcn_cvt_pk_f32_fp8((int)v, true);
    }
    int eb = rs;
    for (; eb + 32 <= re; eb += 32) {       // wave-uniform, no masks
        int e = eb + grp;
        int u0 = csrc[e];      int u1 = csrc[e + 4];
        int u2 = csrc[e + 8];  int u3 = csrc[e + 12];
        int u4 = csrc[e + 16]; int u5 = csrc[e + 20];
        int u6 = csrc[e + 24]; int u7 = csrc[e + 28];
        unsigned v0 = hp[((size_t)u0 << 4) + sub];
        unsigned v1 = hp[((size_t)u1 << 4) + sub];
        unsigned v2 = hp[((size_t)u2 << 4) + sub];
        unsigned v3 = hp[((size_t)u3 << 4) + sub];
        unsigned v4 = hp[((size_t)u4 << 4) + sub];
        unsigned v5 = hp[((size_t)u5 << 4) + sub];
        unsigned v6 = hp[((size_t)u6 << 4) + sub];
        unsigned v7 = hp[((size_t)u7 << 4) + sub];
        A += __builtin_amdgcn_cvt_pk_f32_fp8((int)v0, false);
        B += __builtin_amdgcn_cvt_pk_f32_fp8((int)v0, true);
        A += __builtin_amdgcn_cvt_pk_f32_fp8((int)v1, false);
        B += __builtin_amdgcn_cvt_pk_f32_fp8((int)v1, true);
        A += __builtin_amdgcn_cvt_pk_f32_fp8((int)v2, false);
        B += __builtin_amdgcn_cvt_pk_f32_fp8((int)v2, true);
        A += __builtin_amdgcn_cvt_pk_f32_fp8((int)v3, false);
        B += __builtin_amdgcn_cvt_pk_f32_fp8((int)v3, true);
        A += __builtin_amdgcn_cvt_pk_f32_fp8((int)v4, false);
        B += __builtin_amdgcn_cvt_pk_f32_fp8((int)v4, true);
        A += __builtin_amdgcn_cvt_pk_f32_fp8((int)v5, false);
        B += __builtin_amdgcn_cvt_pk_f32_fp8((int)v5, true);
        A += __builtin_amdgcn_cvt_pk_f32_fp8((int)v6, false);
        B += __builtin_amdgcn_cvt_pk_f32_fp8((int)v6, true);
        A += __builtin_amdgcn_cvt_pk_f32_fp8((int)v7, false);
        B += __builtin_amdgcn_cvt_pk_f32_fp8((int)v7, true);
    }
    int e = eb + grp;                       // masked tail, one iteration
    if (e < re) {
        int e1 = min(e + 4,  re - 1);
        int e2 = min(e + 8,  re - 1);
        int e3 = min(e + 12, re - 1);
        int e4 = min(e + 16, re - 1);
        int e5 = min(e + 20, re - 1);
        int e6 = min(e + 24, re - 1);
        int e7 = min(e + 28, re - 1);
        int u0 = csrc[e];
        int u1 = csrc[e1];
        int u2 = csrc[e2];
        int u3 = csrc[e3];
        int u4 = csrc[e4];
        int u5 = csrc[e5];
        int u6 = csrc[e6];
        int u7 = csrc[e7];
        unsigned v0 = hp[((size_t)u0 << 4) + sub];
        unsigned v1 = hp[((size_t)u1 << 4) + sub];
        unsigned v2 = hp[((size_t)u2 << 4) + sub];
        unsigned v3 = hp[((size_t)u3 << 4) + sub];
        unsigned v4 = hp[((size_t)u4 << 4) + sub];
        unsigned v5 = hp[((size_t)u5 << 4) + sub];
        unsigned v6 = hp[((size_t)u6 << 4) + sub];
        unsigned v7 = hp[((size_t)u7 << 4) + sub];
        float m1 = (e + 4  < re) ? 1.f : 0.f;
        float m2 = (e + 8  < re) ? 1.f : 0.f;
        float m3 = (e + 12 < re) ? 1.f : 0.f;
        float m4 = (e + 16 < re) ? 1.f : 0.f;
        float m5 = (e + 20 < re) ? 1.f : 0.f;
        float m6 = (e + 24 < re) ? 1.f : 0.f;
        float m7 = (e + 28 < re) ? 1.f : 0.f;
        A += __builtin_amdgcn_cvt_pk_f32_fp8((int)v0, false);
        B += __builtin_amdgcn_cvt_pk_f32_fp8((int)v0, true);
        f32x2 M1 = {m1, m1}, M2 = {m2, m2}, M3 = {m3, m3};
        f32x2 M4 = {m4, m4}, M5 = {m5, m5}, M6 = {m6, m6}, M7 = {m7, m7};
        A += M1 * __builtin_amdgcn_cvt_pk_f32_fp8((int)v1, false);
        B += M1 * __builtin_amdgcn_cvt_pk_f32_fp8((int)v1, true);
        A += M2 * __builtin_amdgcn_cvt_pk_f32_fp8((int)v2, false);
        B += M2 * __builtin_amdgcn_cvt_pk_f32_fp8((int)v2, true);
        A += M3 * __builtin_amdgcn_cvt_pk_f32_fp8((int)v3, false);
        B += M3 * __builtin_amdgcn_cvt_pk_f32_fp8((int)v3, true);
        A += M4 * __builtin_amdgcn_cvt_pk_f32_fp8((int)v4, false);
        B += M4 * __builtin_amdgcn_cvt_pk_f32_fp8((int)v4, true);
        A += M5 * __builtin_amdgcn_cvt_pk_f32_fp8((int)v5, false);
        B += M5 * __builtin_amdgcn_cvt_pk_f32_fp8((int)v5, true);
        A += M6 * __builtin_amdgcn_cvt_pk_f32_fp8((int)v6, false);
        B += M6 * __builtin_amdgcn_cvt_pk_f32_fp8((int)v6, true);
        A += M7 * __builtin_amdgcn_cvt_pk_f32_fp8((int)v7, false);
        B += M7 * __builtin_amdgcn_cvt_pk_f32_fp8((int)v7, true);
    }
    float a0 = A[0], a1 = A[1], a2 = B[0], a3 = B[1];
    a0 += __shfl_xor(a0, 16, 64); a0 += __shfl_xor(a0, 32, 64);
    a1 += __shfl_xor(a1, 16, 64); a1 += __shfl_xor(a1, 32, 64);
    a2 += __shfl_xor(a2, 16, 64); a2 += __shfl_xor(a2, 32, 64);
    a3 += __shfl_xor(a3, 16, 64); a3 += __shfl_xor(a3, 32, 64);
    if (grp == 0) {
        float* op = acc + ((size_t)w << 6) + sub;
        op[0]  = a0;
        op[16] = a1;
        op[32] = a2;
        op[48] = a3;
    }
}

// a = relu(dinv*acc + b1); hs2 = fp8(dinv * (a @ W2)) via MFMA; frag preload
__global__ __launch_bounds__(256) void k_xform2(const float* __restrict__ acc_in,
        const uint4* __restrict__ W2fr, const float* __restrict__ b1,
        const float* __restrict__ dinv, unsigned int* __restrict__ hs2, int N, int ntiles) {
    int t = threadIdx.x;
    int lane = t & 63, wid = t >> 6;
    int r16 = lane & 15, kg = lane >> 4;
    half8 bf[4][2];
    #pragma unroll
    for (int ct = 0; ct < 4; ++ct)
        #pragma unroll
        for (int kt = 0; kt < 2; ++kt)
            bf[ct][kt] = *(const half8*)&W2fr[(ct * 2 + kt) * 64 + lane];
    float b1r[2][8];
    #pragma unroll
    for (int kt = 0; kt < 2; ++kt)
        #pragma unroll
        for (int j = 0; j < 8; ++j) b1r[kt][j] = b1[kt * 32 + kg * 8 + j];
    int wtile = blockIdx.x * 4 + wid;
    int nw = gridDim.x * 4;
    for (int tile = wtile; tile < ntiles; tile += nw) {
        int v0 = tile * 16;
        int rowA = min(v0 + r16, N - 1);
        float da = dinv[rowA];
        const float* ap = acc_in + ((size_t)rowA << 6) + kg * 8;
        half8 af[2];
        #pragma unroll
        for (int kt = 0; kt < 2; ++kt) {
            float4 p = *(const float4*)(ap + kt * 32);
            float4 q = *(const float4*)(ap + kt * 32 + 4);
            half8 a;
            a[0] = (_Float16)fmaxf(fmaf(da, p.x, b1r[kt][0]), 0.f);
            a[1] = (_Float16)fmaxf(fmaf(da, p.y, b1r[kt][1]), 0.f);
            a[2] = (_Float16)fmaxf(fmaf(da, p.z, b1r[kt][2]), 0.f);
            a[3] = (_Float16)fmaxf(fmaf(da, p.w, b1r[kt][3]), 0.f);
            a[4] = (_Float16)fmaxf(fmaf(da, q.x, b1r[kt][4]), 0.f);
            a[5] = (_Float16)fmaxf(fmaf(da, q.y, b1r[kt][5]), 0.f);
            a[6] = (_Float16)fmaxf(fmaf(da, q.z, b1r[kt][6]), 0.f);
            a[7] = (_Float16)fmaxf(fmaf(da, q.w, b1r[kt][7]), 0.f);
            af[kt] = a;
        }
        f32x4 acc0 = {0,0,0,0}, acc1 = {0,0,0,0}, acc2 = {0,0,0,0}, acc3 = {0,0,0,0};
        #pragma unroll
        for (int kt = 0; kt < 2; ++kt) {
            acc0 = __builtin_amdgcn_mfma_f32_16x16x32_f16(af[kt], bf[0][kt], acc0, 0, 0, 0);
            acc1 = __builtin_amdgcn_mfma_f32_16x16x32_f16(af[kt], bf[1][kt], acc1, 0, 0, 0);
            acc2 = __builtin_amdgcn_mfma_f32_16x16x32_f16(af[kt], bf[2][kt], acc2, 0, 0, 0);
            acc3 = __builtin_amdgcn_mfma_f32_16x16x32_f16(af[kt], bf[3][kt], acc3, 0, 0, 0);
        }
        #pragma unroll
        for (int r = 0; r < 4; ++r) {
            int node = v0 + kg * 4 + r;
            if (node < N) {
                float d = dinv[node];
                int pk = __builtin_amdgcn_cvt_pk_fp8_f32(d * acc0[r], d * acc1[r], 0, false);
                pk     = __builtin_amdgcn_cvt_pk_fp8_f32(d * acc2[r], d * acc3[r], pk, true);
                hs2[((size_t)node << 4) + r16] = (unsigned int)pk;
            }
        }
    }
}

// a = relu(dinv*acc2 + b2); z = a @ Wf + bf; out = log_softmax(z); frag preload
__global__ __launch_bounds__(256) void k_final(const float* __restrict__ acc2,
        const uint4* __restrict__ Wffr, const float* __restrict__ b2,
        const float* __restrict__ bf, const float* __restrict__ dinv,
        float* __restrict__ out, int N, int ntiles) {
    int t = threadIdx.x;
    int lane = t & 63, wid = t >> 6;
    int r16 = lane & 15, kg = lane >> 4;
    half8 bfr[3][2];
    #pragma unroll
    for (int ct = 0; ct < 3; ++ct)
        #pragma unroll
        for (int kt = 0; kt < 2; ++kt)
            bfr[ct][kt] = *(const half8*)&Wffr[(ct * 2 + kt) * 64 + lane];
    float b2r[2][8];
    #pragma unroll
    for (int kt = 0; kt < 2; ++kt)
        #pragma unroll
        for (int j = 0; j < 8; ++j) b2r[kt][j] = b2[kt * 32 + kg * 8 + j];
    float bf0 = bf[r16];
    float bf1 = bf[16 + r16];
    float bf2 = (r16 < 8) ? bf[32 + r16] : 0.f;
    int wtile = blockIdx.x * 4 + wid;
    int nw = gridDim.x * 4;
    for (int tile = wtile; tile < ntiles; tile += nw) {
        int v0 = tile * 16;
        int rowA = min(v0 + r16, N - 1);
        float da = dinv[rowA];
        const float* ap = acc2 + ((size_t)rowA << 6) + kg * 8;
        half8 af[2];
        #pragma unroll
        for (int kt = 0; kt < 2; ++kt) {
            float4 p = *(const float4*)(ap + kt * 32);
            float4 q = *(const float4*)(ap + kt * 32 + 4);
            half8 a;
            a[0] = (_Float16)fmaxf(fmaf(da, p.x, b2r[kt][0]), 0.f);
            a[1] = (_Float16)fmaxf(fmaf(da, p.y, b2r[kt][1]), 0.f);
            a[2] = (_Float16)fmaxf(fmaf(da, p.z, b2r[kt][2]), 0.f);
            a[3] = (_Float16)fmaxf(fmaf(da, p.w, b2r[kt][3]), 0.f);
            a[4] = (_Float16)fmaxf(fmaf(da, q.x, b2r[kt][4]), 0.f);
            a[5] = (_Float16)fmaxf(fmaf(da, q.y, b2r[kt][5]), 0.f);
            a[6] = (_Float16)fmaxf(fmaf(da, q.z, b2r[kt][6]), 0.f);
            a[7] = (_Float16)fmaxf(fmaf(da, q.w, b2r[kt][7]), 0.f);
            af[kt] = a;
        }
        f32x4 a0 = {0,0,0,0}, a1 = {0,0,0,0}, a2 = {0,0,0,0};
        #pragma unroll
        for (int kt = 0; kt < 2; ++kt) {
            a0 = __builtin_amdgcn_mfma_f32_16x16x32_f16(af[kt], bfr[0][kt], a0, 0, 0, 0);
            a1 = __builtin_amdgcn_mfma_f32_16x16x32_f16(af[kt], bfr[1][kt], a1, 0, 0, 0);
            a2 = __builtin_amdgcn_mfma_f32_16x16x32_f16(af[kt], bfr[2][kt], a2, 0, 0, 0);
        }
        #pragma unroll
        for (int r = 0; r < 4; ++r) {
            float z0 = a0[r] + bf0;
            float z1 = a1[r] + bf1;
            float z2 = (r16 < 8) ? (a2[r] + bf2) : -INFINITY;
            float m = fmaxf(fmaxf(z0, z1), z2);
            #pragma unroll
            for (int o = 8; o; o >>= 1) m = fmaxf(m, __shfl_xor(m, o, 64));
            float s = expf(z0 - m) + expf(z1 - m) + ((r16 < 8) ? expf(z2 - m) : 0.f);
            #pragma unroll
            for (int o = 8; o; o >>= 1) s += __shfl_xor(s, o, 64);
            float ls = m + logf(s);
            int node = v0 + kg * 4 + r;
            if (node < N) {
                float* op = out + (size_t)node * 40;
                op[r16]      = z0 - ls;
                op[16 + r16] = z1 - ls;
                if (r16 < 8) op[32 + r16] = z2 - ls;
            }
        }
    }
}

extern "C" void kernel_launch(void* const* d_in, const int* in_sizes, int n_in,
                              void* d_out, int out_size, void* d_ws, size_t ws_size,
                              hipStream_t stream) {
    const float* x  = (const float*)d_in[0];
    const int*   ei = (const int*)d_in[1];   // [2, E]: row 0 = src, row 1 = dst
    const float* W1 = (const float*)d_in[2];
    const float* b1 = (const float*)d_in[3];
    const float* W2 = (const float*)d_in[4];
    const float* b2 = (const float*)d_in[5];
    const float* Wf = (const float*)d_in[6];
    const float* bf = (const float*)d_in[7];
    float* out = (float*)d_out;

    const int N = in_sizes[0] / 128;
    const int E = in_sizes[1] / 2;
    const int* src = ei;
    const int* dst = ei + E;
    const int NB = (N + 63) >> BSH;          // 64-node buckets (<=2048)

    auto align = [](size_t s) { return (s + 255) & ~(size_t)255; };
    char* ws = (char*)d_ws;
    size_t o = 0;
    int2*  rcp     = (int2*)(ws + o);  o += align((size_t)N * 8);
    float* dinv    = (float*)(ws + o); o += align((size_t)N * 4);
    int*   cursor1 = (int*)(ws + o);   o += align(2048 * 4);
    uint4* W1fr    = (uint4*)(ws + o); o += align(16 * 64 * 16);
    uint4* W2fr    = (uint4*)(ws + o); o += align(8 * 64 * 16);
    uint4* Wffr    = (uint4*)(ws + o); o += align(6 * 64 * 16);
    int*   csrc    = (int*)(ws + o);   o += align((size_t)NB * CAP * 4);
    unsigned int* B1 = (unsigned int*)(ws + o); o += align((size_t)N * 64);  // hs fp8
    float*  B2     = (float*)(ws + o);  o += align((size_t)N * 64 * 4);      // acc
    unsigned int* tmp = (unsigned int*)B2;   // alias: NB*CAP*4 = 19.2MB < 25.6MB

    int blkT  = (E + T1 - 1) / T1;
    int ntile = (N + 15) / 16;
    int gX = 512;                     // persistent MFMA blocks (4 waves each)

    k_prep <<<1,   1024, 0, stream>>>(W1, W2, Wf, cursor1, W1fr, W2fr, Wffr, NB);
    k_pass1<<<blkT, 256, 0, stream>>>(src, dst, cursor1, tmp, E, NB);
    k_p2x  <<<NB,   256, 0, stream>>>(tmp, cursor1, rcp, csrc, dinv, x, W1fr, B1, N);

    int blkAgg = (N * 64 + 255) / 256;  // one wave per node
    k_agg   <<<blkAgg, 256, 0, stream>>>(rcp, csrc, B1, B2, N);
    k_xform2<<<gX, 256, 0, stream>>>(B2, W2fr, b1, dinv, B1, N, ntile);
    k_agg   <<<blkAgg, 256, 0, stream>>>(rcp, csrc, B1, B2, N);
    k_final <<<gX, 256, 0, stream>>>(B2, Wffr, b2, bf, dinv, out, N, ntile);
}

// Round 19
// 195.844 us; speedup vs baseline: 1.0544x; 1.0544x over previous
//
#include <hip/hip_runtime.h>
#include <hip/hip_fp16.h>
#include <cstdint>
#include <cstddef>
#include <cmath>

// ---------------------------------------------------------------------------
// GCN via CSR aggregation:
//   k_prep: cursor init + precompute W1/W2/Wf MFMA fragments (fp16 frag arrays)
//   binning: fixed-capacity dst-buckets (128 nodes, CAP=6144) -> k_pass1
//            packs edges into tmp runs -> k_p2x: 2-copy LDS histogram ->
//            2-wave shfl scan -> rcp/dinv -> 2-copy cursor scatter -> fused
//            xform1 MFMA tail for its 128 nodes.
//   agg: one wave per node, 4 lane-groups of 16, fp8 rows; unroll-8,
//        wave-uniform main loop (packed f32x2 adds) + single predicated tail.
//   xform2/final: MFMA 16x16x32 f16 persistent blocks, fp8 pack/unpack via
//   v_cvt_pk_fp8_f32 / v_cvt_pk_f32_fp8 (byte b of uint s = channel s+16b).
//   tmp aliases B2 (dead before first k_agg write).
// ---------------------------------------------------------------------------

#define T1  4096    // edges per pass-1 tile
#define BSH 7       // 128-node buckets
#define CAP 6144    // bucket capacity (avg 4092, sigma ~64)

typedef _Float16 half8 __attribute__((ext_vector_type(8)));
typedef float f32x4 __attribute__((ext_vector_type(4)));
typedef float f32x2 __attribute__((ext_vector_type(2)));

// cursor init + weight-fragment precompute (one block)
__global__ __launch_bounds__(1024) void k_prep(const float* __restrict__ W1,
        const float* __restrict__ W2, const float* __restrict__ Wf,
        int* __restrict__ cursor1, uint4* __restrict__ W1fr,
        uint4* __restrict__ W2fr, uint4* __restrict__ Wffr, int NB) {
    int t = threadIdx.x;
    for (int i = t; i < NB; i += 1024) cursor1[i] = i * CAP;
    if (t < 64) {
        int r16 = t & 15, kg = t >> 4;
        #pragma unroll
        for (int ct = 0; ct < 4; ++ct)
            #pragma unroll
            for (int kt = 0; kt < 4; ++kt) {
                half8 h;
                #pragma unroll
                for (int j = 0; j < 8; ++j)
                    h[j] = (_Float16)W1[(kt * 32 + kg * 8 + j) * 64 + ct * 16 + r16];
                W1fr[(ct * 4 + kt) * 64 + t] = *(uint4*)&h;
            }
        #pragma unroll
        for (int ct = 0; ct < 4; ++ct)
            #pragma unroll
            for (int kt = 0; kt < 2; ++kt) {
                half8 h;
                #pragma unroll
                for (int j = 0; j < 8; ++j)
                    h[j] = (_Float16)W2[(kt * 32 + kg * 8 + j) * 64 + ct * 16 + r16];
                W2fr[(ct * 2 + kt) * 64 + t] = *(uint4*)&h;
            }
        #pragma unroll
        for (int ct = 0; ct < 3; ++ct)
            #pragma unroll
            for (int kt = 0; kt < 2; ++kt) {
                int col = ct * 16 + r16;
                half8 h;
                #pragma unroll
                for (int j = 0; j < 8; ++j)
                    h[j] = (col < 40) ? (_Float16)Wf[(kt * 32 + kg * 8 + j) * 40 + col]
                                      : (_Float16)0.f;
                Wffr[(ct * 2 + kt) * 64 + t] = *(uint4*)&h;
            }
    }
}

__global__ __launch_bounds__(256) void k_pass1(const int* __restrict__ src,
        const int* __restrict__ dst, int* __restrict__ cursor1,
        unsigned int* __restrict__ tmp, int E, int NB) {
    __shared__ unsigned int pack[T1];                 // 16 KB
    __shared__ unsigned short bkt[T1];                //  8 KB
    __shared__ int h[1024], hs_[1024], gbase[1024];   // 12 KB
    int t = threadIdx.x;
    for (int i = t; i < 1024; i += 256) h[i] = 0;
    __syncthreads();
    int base = blockIdx.x * T1;
    int n = min(T1, E - base);
    unsigned int pk[16];
    int bl[16];
    #pragma unroll
    for (int i = 0; i < 16; ++i) {
        int idx = i * 256 + t;
        if (idx < n) {
            int s_ = src[base + idx], d = dst[base + idx];
            int b = d >> BSH;
            pk[i] = (unsigned int)s_ | ((unsigned int)(d & 127) << 17);
            int lo = atomicAdd(&h[b], 1);
            bl[i] = (b << 13) | lo;
        } else bl[i] = -1;
    }
    __syncthreads();
    #pragma unroll
    for (int i = 0; i < 4; ++i) hs_[t + i * 256] = h[t + i * 256];
    __syncthreads();
    for (int st = 1; st < 1024; st <<= 1) {
        int tp[4];
        #pragma unroll
        for (int i = 0; i < 4; ++i) {
            int idx = t + i * 256;
            tp[i] = (idx >= st) ? hs_[idx - st] : 0;
        }
        __syncthreads();
        #pragma unroll
        for (int i = 0; i < 4; ++i) hs_[t + i * 256] += tp[i];
        __syncthreads();
    }
    for (int i = t; i < NB; i += 256)
        gbase[i] = h[i] ? atomicAdd(&cursor1[i], h[i]) : 0;
    __syncthreads();
    #pragma unroll
    for (int i = 0; i < 16; ++i) {
        if (bl[i] >= 0) {
            int b = bl[i] >> 13, lo = bl[i] & 8191;
            int slot = hs_[b] - h[b] + lo;
            pack[slot] = pk[i];
            bkt[slot]  = (unsigned short)b;
        }
    }
    __syncthreads();
    for (int s_ = t; s_ < n; s_ += 256) {
        int b = bkt[s_];
        tmp[gbase[b] + (s_ - (hs_[b] - h[b]))] = pack[s_];
    }
}

// per-bucket (128 nodes): 2-copy histogram -> 2-wave shfl scan -> rcp/dinv ->
// 2-copy cursor scatter -> fused xform1 MFMA tail (2 tiles per wave).
__global__ __launch_bounds__(256) void k_p2x(const unsigned int* __restrict__ tmp,
        const int* __restrict__ cursor1, int2* __restrict__ rcp,
        int* __restrict__ csrc, float* __restrict__ dinv,
        const float* __restrict__ x, const uint4* __restrict__ W1fr,
        unsigned int* __restrict__ hs, int N) {
    __shared__ int c[2][128], cur[2][128];
    __shared__ float sdinv[128];
    __shared__ int wsum;
    int t = threadIdx.x, b = blockIdx.x;
    c[t >> 7][t & 127] = 0;
    __syncthreads();
    int s0 = b * CAP, s1 = cursor1[b];
    int half = t >> 7;
    for (int s = s0 + t; s < s1; s += 256)
        atomicAdd(&c[half][(tmp[s] >> 17) & 127], 1);
    __syncthreads();
    int c0v = 0, totv = 0, vv = 0;
    if (t < 128) {
        c0v = c[0][t];
        totv = c0v + c[1][t];
        vv = totv;                        // inclusive scan within each wave
        #pragma unroll
        for (int o = 1; o < 64; o <<= 1) {
            int u = __shfl_up(vv, o, 64);
            if ((t & 63) >= o) vv += u;
        }
        if (t == 63) wsum = vv;           // total of entries 0..63
    }
    __syncthreads();
    if (t < 128) {
        if (t >= 64) vv += wsum;
        int rp = s0 + vv - totv;          // exclusive prefix
        float dv = rsqrtf((float)totv + 1.0f);   // +1 self loop
        sdinv[t] = dv;
        int node = b * 128 + t;
        if (node < N) {
            rcp[node]  = make_int2(rp, totv);
            dinv[node] = dv;
        }
        cur[0][t] = rp;
        cur[1][t] = rp + c0v;
    }
    __syncthreads();
    for (int s = s0 + t; s < s1; s += 256) {
        unsigned int p = tmp[s];
        int q = atomicAdd(&cur[half][(p >> 17) & 127], 1);
        csrc[q] = (int)(p & 0x1FFFFu);
    }
    __syncthreads();
    // ---------------- fused xform1 MFMA tail ------------------------------
    int lane = t & 63, wid = t >> 6;
    int r16 = lane & 15, kg = lane >> 4;
    half8 bf[4][4];                       // [coltile][ktile]
    #pragma unroll
    for (int ct = 0; ct < 4; ++ct)
        #pragma unroll
        for (int kt = 0; kt < 4; ++kt)
            bf[ct][kt] = *(const half8*)&W1fr[(ct * 4 + kt) * 64 + lane];
    #pragma unroll
    for (int lt2 = 0; lt2 < 2; ++lt2) {   // 2 tiles per wave (8 per block)
        int lt = wid * 2 + lt2;
        int v0 = b * 128 + lt * 16;
        int rowA = min(v0 + r16, N - 1);
        const float* xp = x + (size_t)rowA * 128 + kg * 8;
        half8 af[4];
        #pragma unroll
        for (int kt = 0; kt < 4; ++kt) {
            float4 p = *(const float4*)(xp + kt * 32);
            float4 q = *(const float4*)(xp + kt * 32 + 4);
            half8 a;
            a[0] = (_Float16)p.x; a[1] = (_Float16)p.y;
            a[2] = (_Float16)p.z; a[3] = (_Float16)p.w;
            a[4] = (_Float16)q.x; a[5] = (_Float16)q.y;
            a[6] = (_Float16)q.z; a[7] = (_Float16)q.w;
            af[kt] = a;
        }
        f32x4 acc0 = {0,0,0,0}, acc1 = {0,0,0,0}, acc2 = {0,0,0,0}, acc3 = {0,0,0,0};
        #pragma unroll
        for (int kt = 0; kt < 4; ++kt) {
            acc0 = __builtin_amdgcn_mfma_f32_16x16x32_f16(af[kt], bf[0][kt], acc0, 0, 0, 0);
            acc1 = __builtin_amdgcn_mfma_f32_16x16x32_f16(af[kt], bf[1][kt], acc1, 0, 0, 0);
            acc2 = __builtin_amdgcn_mfma_f32_16x16x32_f16(af[kt], bf[2][kt], acc2, 0, 0, 0);
            acc3 = __builtin_amdgcn_mfma_f32_16x16x32_f16(af[kt], bf[3][kt], acc3, 0, 0, 0);
        }
        #pragma unroll
        for (int r = 0; r < 4; ++r) {
            int nd = v0 + kg * 4 + r;
            if (nd < N) {
                float d = sdinv[lt * 16 + kg * 4 + r];
                int pk = __builtin_amdgcn_cvt_pk_fp8_f32(d * acc0[r], d * acc1[r], 0, false);
                pk     = __builtin_amdgcn_cvt_pk_fp8_f32(d * acc2[r], d * acc3[r], pk, true);
                hs[((size_t)nd << 4) + r16] = (unsigned int)pk;
            }
        }
    }
}

// --- one wave per node, 4 lane-groups of 16; uniform main + masked tail ----
// fp8 row = 16 uints; byte b of uint s = channel s + 16*b.
__global__ __launch_bounds__(256) void k_agg(const int2* __restrict__ rcp,
        const int* __restrict__ csrc, const unsigned int* __restrict__ hp,
        float* __restrict__ acc, int N) {
    int w = (blockIdx.x * 256 + threadIdx.x) >> 6;
    int lane = threadIdx.x & 63;
    if (w >= N) return;
    int grp = lane >> 4, sub = lane & 15;
    int2 rc = rcp[w];
    int rs = rc.x, re = rc.x + rc.y;
    f32x2 A = {0.f, 0.f}, B = {0.f, 0.f};   // {sub, sub+16}, {sub+32, sub+48}
    if (grp == 0) {                                     // self loop, once
        unsigned v = hp[((size_t)w << 4) + sub];
        A = __builtin_amdgcn_cvt_pk_f32_fp8((int)v, false);
        B = __builtin_amdgcn_cvt_pk_f32_fp8((int)v, true);
    }
    int eb = rs;
    for (; eb + 32 <= re; eb += 32) {       // wave-uniform, no masks
        int e = eb + grp;
        int u0 = csrc[e];      int u1 = csrc[e + 4];
        int u2 = csrc[e + 8];  int u3 = csrc[e + 12];
        int u4 = csrc[e + 16]; int u5 = csrc[e + 20];
        int u6 = csrc[e + 24]; int u7 = csrc[e + 28];
        unsigned v0 = hp[((size_t)u0 << 4) + sub];
        unsigned v1 = hp[((size_t)u1 << 4) + sub];
        unsigned v2 = hp[((size_t)u2 << 4) + sub];
        unsigned v3 = hp[((size_t)u3 << 4) + sub];
        unsigned v4 = hp[((size_t)u4 << 4) + sub];
        unsigned v5 = hp[((size_t)u5 << 4) + sub];
        unsigned v6 = hp[((size_t)u6 << 4) + sub];
        unsigned v7 = hp[((size_t)u7 << 4) + sub];
        A += __builtin_amdgcn_cvt_pk_f32_fp8((int)v0, false);
        B += __builtin_amdgcn_cvt_pk_f32_fp8((int)v0, true);
        A += __builtin_amdgcn_cvt_pk_f32_fp8((int)v1, false);
        B += __builtin_amdgcn_cvt_pk_f32_fp8((int)v1, true);
        A += __builtin_amdgcn_cvt_pk_f32_fp8((int)v2, false);
        B += __builtin_amdgcn_cvt_pk_f32_fp8((int)v2, true);
        A += __builtin_amdgcn_cvt_pk_f32_fp8((int)v3, false);
        B += __builtin_amdgcn_cvt_pk_f32_fp8((int)v3, true);
        A += __builtin_amdgcn_cvt_pk_f32_fp8((int)v4, false);
        B += __builtin_amdgcn_cvt_pk_f32_fp8((int)v4, true);
        A += __builtin_amdgcn_cvt_pk_f32_fp8((int)v5, false);
        B += __builtin_amdgcn_cvt_pk_f32_fp8((int)v5, true);
        A += __builtin_amdgcn_cvt_pk_f32_fp8((int)v6, false);
        B += __builtin_amdgcn_cvt_pk_f32_fp8((int)v6, true);
        A += __builtin_amdgcn_cvt_pk_f32_fp8((int)v7, false);
        B += __builtin_amdgcn_cvt_pk_f32_fp8((int)v7, true);
    }
    int e = eb + grp;                       // masked tail, one iteration
    if (e < re) {
        int e1 = min(e + 4,  re - 1);
        int e2 = min(e + 8,  re - 1);
        int e3 = min(e + 12, re - 1);
        int e4 = min(e + 16, re - 1);
        int e5 = min(e + 20, re - 1);
        int e6 = min(e + 24, re - 1);
        int e7 = min(e + 28, re - 1);
        int u0 = csrc[e];
        int u1 = csrc[e1];
        int u2 = csrc[e2];
        int u3 = csrc[e3];
        int u4 = csrc[e4];
        int u5 = csrc[e5];
        int u6 = csrc[e6];
        int u7 = csrc[e7];
        unsigned v0 = hp[((size_t)u0 << 4) + sub];
        unsigned v1 = hp[((size_t)u1 << 4) + sub];
        unsigned v2 = hp[((size_t)u2 << 4) + sub];
        unsigned v3 = hp[((size_t)u3 << 4) + sub];
        unsigned v4 = hp[((size_t)u4 << 4) + sub];
        unsigned v5 = hp[((size_t)u5 << 4) + sub];
        unsigned v6 = hp[((size_t)u6 << 4) + sub];
        unsigned v7 = hp[((size_t)u7 << 4) + sub];
        float m1 = (e + 4  < re) ? 1.f : 0.f;
        float m2 = (e + 8  < re) ? 1.f : 0.f;
        float m3 = (e + 12 < re) ? 1.f : 0.f;
        float m4 = (e + 16 < re) ? 1.f : 0.f;
        float m5 = (e + 20 < re) ? 1.f : 0.f;
        float m6 = (e + 24 < re) ? 1.f : 0.f;
        float m7 = (e + 28 < re) ? 1.f : 0.f;
        A += __builtin_amdgcn_cvt_pk_f32_fp8((int)v0, false);
        B += __builtin_amdgcn_cvt_pk_f32_fp8((int)v0, true);
        f32x2 M1 = {m1, m1}, M2 = {m2, m2}, M3 = {m3, m3};
        f32x2 M4 = {m4, m4}, M5 = {m5, m5}, M6 = {m6, m6}, M7 = {m7, m7};
        A += M1 * __builtin_amdgcn_cvt_pk_f32_fp8((int)v1, false);
        B += M1 * __builtin_amdgcn_cvt_pk_f32_fp8((int)v1, true);
        A += M2 * __builtin_amdgcn_cvt_pk_f32_fp8((int)v2, false);
        B += M2 * __builtin_amdgcn_cvt_pk_f32_fp8((int)v2, true);
        A += M3 * __builtin_amdgcn_cvt_pk_f32_fp8((int)v3, false);
        B += M3 * __builtin_amdgcn_cvt_pk_f32_fp8((int)v3, true);
        A += M4 * __builtin_amdgcn_cvt_pk_f32_fp8((int)v4, false);
        B += M4 * __builtin_amdgcn_cvt_pk_f32_fp8((int)v4, true);
        A += M5 * __builtin_amdgcn_cvt_pk_f32_fp8((int)v5, false);
        B += M5 * __builtin_amdgcn_cvt_pk_f32_fp8((int)v5, true);
        A += M6 * __builtin_amdgcn_cvt_pk_f32_fp8((int)v6, false);
        B += M6 * __builtin_amdgcn_cvt_pk_f32_fp8((int)v6, true);
        A += M7 * __builtin_amdgcn_cvt_pk_f32_fp8((int)v7, false);
        B += M7 * __builtin_amdgcn_cvt_pk_f32_fp8((int)v7, true);
    }
    float a0 = A[0], a1 = A[1], a2 = B[0], a3 = B[1];
    a0 += __shfl_xor(a0, 16, 64); a0 += __shfl_xor(a0, 32, 64);
    a1 += __shfl_xor(a1, 16, 64); a1 += __shfl_xor(a1, 32, 64);
    a2 += __shfl_xor(a2, 16, 64); a2 += __shfl_xor(a2, 32, 64);
    a3 += __shfl_xor(a3, 16, 64); a3 += __shfl_xor(a3, 32, 64);
    if (grp == 0) {
        float* op = acc + ((size_t)w << 6) + sub;
        op[0]  = a0;
        op[16] = a1;
        op[32] = a2;
        op[48] = a3;
    }
}

// a = relu(dinv*acc + b1); hs2 = fp8(dinv * (a @ W2)) via MFMA; frag preload
__global__ __launch_bounds__(256) void k_xform2(const float* __restrict__ acc_in,
        const uint4* __restrict__ W2fr, const float* __restrict__ b1,
        const float* __restrict__ dinv, unsigned int* __restrict__ hs2, int N, int ntiles) {
    int t = threadIdx.x;
    int lane = t & 63, wid = t >> 6;
    int r16 = lane & 15, kg = lane >> 4;
    half8 bf[4][2];
    #pragma unroll
    for (int ct = 0; ct < 4; ++ct)
        #pragma unroll
        for (int kt = 0; kt < 2; ++kt)
            bf[ct][kt] = *(const half8*)&W2fr[(ct * 2 + kt) * 64 + lane];
    float b1r[2][8];
    #pragma unroll
    for (int kt = 0; kt < 2; ++kt)
        #pragma unroll
        for (int j = 0; j < 8; ++j) b1r[kt][j] = b1[kt * 32 + kg * 8 + j];
    int wtile = blockIdx.x * 4 + wid;
    int nw = gridDim.x * 4;
    for (int tile = wtile; tile < ntiles; tile += nw) {
        int v0 = tile * 16;
        int rowA = min(v0 + r16, N - 1);
        float da = dinv[rowA];
        const float* ap = acc_in + ((size_t)rowA << 6) + kg * 8;
        half8 af[2];
        #pragma unroll
        for (int kt = 0; kt < 2; ++kt) {
            float4 p = *(const float4*)(ap + kt * 32);
            float4 q = *(const float4*)(ap + kt * 32 + 4);
            half8 a;
            a[0] = (_Float16)fmaxf(fmaf(da, p.x, b1r[kt][0]), 0.f);
            a[1] = (_Float16)fmaxf(fmaf(da, p.y, b1r[kt][1]), 0.f);
            a[2] = (_Float16)fmaxf(fmaf(da, p.z, b1r[kt][2]), 0.f);
            a[3] = (_Float16)fmaxf(fmaf(da, p.w, b1r[kt][3]), 0.f);
            a[4] = (_Float16)fmaxf(fmaf(da, q.x, b1r[kt][4]), 0.f);
            a[5] = (_Float16)fmaxf(fmaf(da, q.y, b1r[kt][5]), 0.f);
            a[6] = (_Float16)fmaxf(fmaf(da, q.z, b1r[kt][6]), 0.f);
            a[7] = (_Float16)fmaxf(fmaf(da, q.w, b1r[kt][7]), 0.f);
            af[kt] = a;
        }
        f32x4 acc0 = {0,0,0,0}, acc1 = {0,0,0,0}, acc2 = {0,0,0,0}, acc3 = {0,0,0,0};
        #pragma unroll
        for (int kt = 0; kt < 2; ++kt) {
            acc0 = __builtin_amdgcn_mfma_f32_16x16x32_f16(af[kt], bf[0][kt], acc0, 0, 0, 0);
            acc1 = __builtin_amdgcn_mfma_f32_16x16x32_f16(af[kt], bf[1][kt], acc1, 0, 0, 0);
            acc2 = __builtin_amdgcn_mfma_f32_16x16x32_f16(af[kt], bf[2][kt], acc2, 0, 0, 0);
            acc3 = __builtin_amdgcn_mfma_f32_16x16x32_f16(af[kt], bf[3][kt], acc3, 0, 0, 0);
        }
        #pragma unroll
        for (int r = 0; r < 4; ++r) {
            int node = v0 + kg * 4 + r;
            if (node < N) {
                float d = dinv[node];
                int pk = __builtin_amdgcn_cvt_pk_fp8_f32(d * acc0[r], d * acc1[r], 0, false);
                pk     = __builtin_amdgcn_cvt_pk_fp8_f32(d * acc2[r], d * acc3[r], pk, true);
                hs2[((size_t)node << 4) + r16] = (unsigned int)pk;
            }
        }
    }
}

// a = relu(dinv*acc2 + b2); z = a @ Wf + bf; out = log_softmax(z); frag preload
__global__ __launch_bounds__(256) void k_final(const float* __restrict__ acc2,
        const uint4* __restrict__ Wffr, const float* __restrict__ b2,
        const float* __restrict__ bf, const float* __restrict__ dinv,
        float* __restrict__ out, int N, int ntiles) {
    int t = threadIdx.x;
    int lane = t & 63, wid = t >> 6;
    int r16 = lane & 15, kg = lane >> 4;
    half8 bfr[3][2];
    #pragma unroll
    for (int ct = 0; ct < 3; ++ct)
        #pragma unroll
        for (int kt = 0; kt < 2; ++kt)
            bfr[ct][kt] = *(const half8*)&Wffr[(ct * 2 + kt) * 64 + lane];
    float b2r[2][8];
    #pragma unroll
    for (int kt = 0; kt < 2; ++kt)
        #pragma unroll
        for (int j = 0; j < 8; ++j) b2r[kt][j] = b2[kt * 32 + kg * 8 + j];
    float bf0 = bf[r16];
    float bf1 = bf[16 + r16];
    float bf2 = (r16 < 8) ? bf[32 + r16] : 0.f;
    int wtile = blockIdx.x * 4 + wid;
    int nw = gridDim.x * 4;
    for (int tile = wtile; tile < ntiles; tile += nw) {
        int v0 = tile * 16;
        int rowA = min(v0 + r16, N - 1);
        float da = dinv[rowA];
        const float* ap = acc2 + ((size_t)rowA << 6) + kg * 8;
        half8 af[2];
        #pragma unroll
        for (int kt = 0; kt < 2; ++kt) {
            float4 p = *(const float4*)(ap + kt * 32);
            float4 q = *(const float4*)(ap + kt * 32 + 4);
            half8 a;
            a[0] = (_Float16)fmaxf(fmaf(da, p.x, b2r[kt][0]), 0.f);
            a[1] = (_Float16)fmaxf(fmaf(da, p.y, b2r[kt][1]), 0.f);
            a[2] = (_Float16)fmaxf(fmaf(da, p.z, b2r[kt][2]), 0.f);
            a[3] = (_Float16)fmaxf(fmaf(da, p.w, b2r[kt][3]), 0.f);
            a[4] = (_Float16)fmaxf(fmaf(da, q.x, b2r[kt][4]), 0.f);
            a[5] = (_Float16)fmaxf(fmaf(da, q.y, b2r[kt][5]), 0.f);
            a[6] = (_Float16)fmaxf(fmaf(da, q.z, b2r[kt][6]), 0.f);
            a[7] = (_Float16)fmaxf(fmaf(da, q.w, b2r[kt][7]), 0.f);
            af[kt] = a;
        }
        f32x4 a0 = {0,0,0,0}, a1 = {0,0,0,0}, a2 = {0,0,0,0};
        #pragma unroll
        for (int kt = 0; kt < 2; ++kt) {
            a0 = __builtin_amdgcn_mfma_f32_16x16x32_f16(af[kt], bfr[0][kt], a0, 0, 0, 0);
            a1 = __builtin_amdgcn_mfma_f32_16x16x32_f16(af[kt], bfr[1][kt], a1, 0, 0, 0);
            a2 = __builtin_amdgcn_mfma_f32_16x16x32_f16(af[kt], bfr[2][kt], a2, 0, 0, 0);
        }
        #pragma unroll
        for (int r = 0; r < 4; ++r) {
            float z0 = a0[r] + bf0;
            float z1 = a1[r] + bf1;
            float z2 = (r16 < 8) ? (a2[r] + bf2) : -INFINITY;
            float m = fmaxf(fmaxf(z0, z1), z2);
            #pragma unroll
            for (int o = 8; o; o >>= 1) m = fmaxf(m, __shfl_xor(m, o, 64));
            float s = expf(z0 - m) + expf(z1 - m) + ((r16 < 8) ? expf(z2 - m) : 0.f);
            #pragma unroll
            for (int o = 8; o; o >>= 1) s += __shfl_xor(s, o, 64);
            float ls = m + logf(s);
            int node = v0 + kg * 4 + r;
            if (node < N) {
                float* op = out + (size_t)node * 40;
                op[r16]      = z0 - ls;
                op[16 + r16] = z1 - ls;
                if (r16 < 8) op[32 + r16] = z2 - ls;
            }
        }
    }
}

extern "C" void kernel_launch(void* const* d_in, const int* in_sizes, int n_in,
                              void* d_out, int out_size, void* d_ws, size_t ws_size,
                              hipStream_t stream) {
    const float* x  = (const float*)d_in[0];
    const int*   ei = (const int*)d_in[1];   // [2, E]: row 0 = src, row 1 = dst
    const float* W1 = (const float*)d_in[2];
    const float* b1 = (const float*)d_in[3];
    const float* W2 = (const float*)d_in[4];
    const float* b2 = (const float*)d_in[5];
    const float* Wf = (const float*)d_in[6];
    const float* bf = (const float*)d_in[7];
    float* out = (float*)d_out;

    const int N = in_sizes[0] / 128;
    const int E = in_sizes[1] / 2;
    const int* src = ei;
    const int* dst = ei + E;
    const int NB = (N + 127) >> BSH;         // 128-node buckets (<=1024)

    auto align = [](size_t s) { return (s + 255) & ~(size_t)255; };
    char* ws = (char*)d_ws;
    size_t o = 0;
    int2*  rcp     = (int2*)(ws + o);  o += align((size_t)N * 8);
    float* dinv    = (float*)(ws + o); o += align((size_t)N * 4);
    int*   cursor1 = (int*)(ws + o);   o += align(1024 * 4);
    uint4* W1fr    = (uint4*)(ws + o); o += align(16 * 64 * 16);
    uint4* W2fr    = (uint4*)(ws + o); o += align(8 * 64 * 16);
    uint4* Wffr    = (uint4*)(ws + o); o += align(6 * 64 * 16);
    int*   csrc    = (int*)(ws + o);   o += align((size_t)NB * CAP * 4);
    unsigned int* B1 = (unsigned int*)(ws + o); o += align((size_t)N * 64);  // hs fp8
    float*  B2     = (float*)(ws + o);  o += align((size_t)N * 64 * 4);      // acc
    unsigned int* tmp = (unsigned int*)B2;   // alias: tmp dead before k_agg writes B2

    int blkT  = (E + T1 - 1) / T1;
    int ntile = (N + 15) / 16;
    int gX = 512;                     // persistent MFMA blocks (4 waves each)

    k_prep <<<1,   1024, 0, stream>>>(W1, W2, Wf, cursor1, W1fr, W2fr, Wffr, NB);
    k_pass1<<<blkT, 256, 0, stream>>>(src, dst, cursor1, tmp, E, NB);
    k_p2x  <<<NB,   256, 0, stream>>>(tmp, cursor1, rcp, csrc, dinv, x, W1fr, B1, N);

    int blkAgg = (N * 64 + 255) / 256;  // one wave per node
    k_agg   <<<blkAgg, 256, 0, stream>>>(rcp, csrc, B1, B2, N);
    k_xform2<<<gX, 256, 0, stream>>>(B2, W2fr, b1, dinv, B1, N, ntile);
    k_agg   <<<blkAgg, 256, 0, stream>>>(rcp, csrc, B1, B2, N);
    k_final <<<gX, 256, 0, stream>>>(B2, Wffr, b2, bf, dinv, out, N, ntile);
}

// Round 20
// 189.712 us; speedup vs baseline: 1.0885x; 1.0323x over previous
//
#include <hip/hip_runtime.h>
#include <hip/hip_fp16.h>
#include <cstdint>
#include <cstddef>
#include <cmath>

// ---------------------------------------------------------------------------
// GCN via CSR aggregation:
//   k_prep: cursor init + precompute W1/W2/Wf MFMA fragments (fp16 frag arrays)
//   binning: fixed-capacity dst-buckets (128 nodes, CAP=6144) -> k_pass1
//            packs edges into tmp runs -> k_p2x (512 thr, 8 waves): per-wave
//            LDS histograms (uint4 streaming) -> 2-wave shfl scan -> rcp/dinv
//            -> per-wave cursor scatter -> fused xform1 MFMA tail (1 tile/wave).
//   agg: one wave per node, 4 lane-groups of 16, fp8 rows; unroll-8,
//        wave-uniform main loop (packed f32x2 adds) + single predicated tail.
//   xform2/final: MFMA 16x16x32 f16 persistent blocks, fp8 pack/unpack via
//   v_cvt_pk_fp8_f32 / v_cvt_pk_f32_fp8 (byte b of uint s = channel s+16b).
//   tmp aliases B2 (dead before first k_agg write).
// ---------------------------------------------------------------------------

#define T1  4096    // edges per pass-1 tile
#define BSH 7       // 128-node buckets
#define CAP 6144    // bucket capacity (avg 4092, sigma ~64); divisible by 4

typedef _Float16 half8 __attribute__((ext_vector_type(8)));
typedef float f32x4 __attribute__((ext_vector_type(4)));
typedef float f32x2 __attribute__((ext_vector_type(2)));

// cursor init + weight-fragment precompute (one block)
__global__ __launch_bounds__(1024) void k_prep(const float* __restrict__ W1,
        const float* __restrict__ W2, const float* __restrict__ Wf,
        int* __restrict__ cursor1, uint4* __restrict__ W1fr,
        uint4* __restrict__ W2fr, uint4* __restrict__ Wffr, int NB) {
    int t = threadIdx.x;
    for (int i = t; i < NB; i += 1024) cursor1[i] = i * CAP;
    if (t < 64) {
        int r16 = t & 15, kg = t >> 4;
        #pragma unroll
        for (int ct = 0; ct < 4; ++ct)
            #pragma unroll
            for (int kt = 0; kt < 4; ++kt) {
                half8 h;
                #pragma unroll
                for (int j = 0; j < 8; ++j)
                    h[j] = (_Float16)W1[(kt * 32 + kg * 8 + j) * 64 + ct * 16 + r16];
                W1fr[(ct * 4 + kt) * 64 + t] = *(uint4*)&h;
            }
        #pragma unroll
        for (int ct = 0; ct < 4; ++ct)
            #pragma unroll
            for (int kt = 0; kt < 2; ++kt) {
                half8 h;
                #pragma unroll
                for (int j = 0; j < 8; ++j)
                    h[j] = (_Float16)W2[(kt * 32 + kg * 8 + j) * 64 + ct * 16 + r16];
                W2fr[(ct * 2 + kt) * 64 + t] = *(uint4*)&h;
            }
        #pragma unroll
        for (int ct = 0; ct < 3; ++ct)
            #pragma unroll
            for (int kt = 0; kt < 2; ++kt) {
                int col = ct * 16 + r16;
                half8 h;
                #pragma unroll
                for (int j = 0; j < 8; ++j)
                    h[j] = (col < 40) ? (_Float16)Wf[(kt * 32 + kg * 8 + j) * 40 + col]
                                      : (_Float16)0.f;
                Wffr[(ct * 2 + kt) * 64 + t] = *(uint4*)&h;
            }
    }
}

__global__ __launch_bounds__(256) void k_pass1(const int* __restrict__ src,
        const int* __restrict__ dst, int* __restrict__ cursor1,
        unsigned int* __restrict__ tmp, int E, int NB) {
    __shared__ unsigned int pack[T1];                 // 16 KB
    __shared__ unsigned short bkt[T1];                //  8 KB
    __shared__ int h[1024], hs_[1024], gbase[1024];   // 12 KB
    int t = threadIdx.x;
    for (int i = t; i < 1024; i += 256) h[i] = 0;
    __syncthreads();
    int base = blockIdx.x * T1;
    int n = min(T1, E - base);
    unsigned int pk[16];
    int bl[16];
    #pragma unroll
    for (int i = 0; i < 16; ++i) {
        int idx = i * 256 + t;
        if (idx < n) {
            int s_ = src[base + idx], d = dst[base + idx];
            int b = d >> BSH;
            pk[i] = (unsigned int)s_ | ((unsigned int)(d & 127) << 17);
            int lo = atomicAdd(&h[b], 1);
            bl[i] = (b << 13) | lo;
        } else bl[i] = -1;
    }
    __syncthreads();
    #pragma unroll
    for (int i = 0; i < 4; ++i) hs_[t + i * 256] = h[t + i * 256];
    __syncthreads();
    for (int st = 1; st < 1024; st <<= 1) {
        int tp[4];
        #pragma unroll
        for (int i = 0; i < 4; ++i) {
            int idx = t + i * 256;
            tp[i] = (idx >= st) ? hs_[idx - st] : 0;
        }
        __syncthreads();
        #pragma unroll
        for (int i = 0; i < 4; ++i) hs_[t + i * 256] += tp[i];
        __syncthreads();
    }
    for (int i = t; i < NB; i += 256)
        gbase[i] = h[i] ? atomicAdd(&cursor1[i], h[i]) : 0;
    __syncthreads();
    #pragma unroll
    for (int i = 0; i < 16; ++i) {
        if (bl[i] >= 0) {
            int b = bl[i] >> 13, lo = bl[i] & 8191;
            int slot = hs_[b] - h[b] + lo;
            pack[slot] = pk[i];
            bkt[slot]  = (unsigned short)b;
        }
    }
    __syncthreads();
    for (int s_ = t; s_ < n; s_ += 256) {
        int b = bkt[s_];
        tmp[gbase[b] + (s_ - (hs_[b] - h[b]))] = pack[s_];
    }
}

// per-bucket (128 nodes), 512 threads / 8 waves:
// per-wave uint4 histogram -> 2-wave shfl scan -> rcp/dinv ->
// per-wave cursor scatter -> fused xform1 MFMA tail (1 tile per wave).
__global__ __launch_bounds__(512) void k_p2x(const unsigned int* __restrict__ tmp,
        const int* __restrict__ cursor1, int2* __restrict__ rcp,
        int* __restrict__ csrc, float* __restrict__ dinv,
        const float* __restrict__ x, const uint4* __restrict__ W1fr,
        unsigned int* __restrict__ hs, int N) {
    __shared__ int c[8][128], cur[8][128];    // 8 KB
    __shared__ float sdinv[128];
    __shared__ int wsum;
    int t = threadIdx.x, b = blockIdx.x;
    int wv = t >> 6;
    for (int i = t; i < 1024; i += 512) ((int*)c)[i] = 0;
    __syncthreads();
    int s0 = b * CAP, s1 = cursor1[b];
    int n = s1 - s0;
    int nv4 = n >> 2, rem = n & 3;
    const uint4* tmp4 = (const uint4*)(tmp + s0);
    // ---- per-wave histogram, uint4 streaming ----
    for (int i = t; i < nv4; i += 512) {
        uint4 v = tmp4[i];
        atomicAdd(&c[wv][(v.x >> 17) & 127], 1);
        atomicAdd(&c[wv][(v.y >> 17) & 127], 1);
        atomicAdd(&c[wv][(v.z >> 17) & 127], 1);
        atomicAdd(&c[wv][(v.w >> 17) & 127], 1);
    }
    if (t < rem)
        atomicAdd(&c[wv][(tmp[s0 + nv4 * 4 + t] >> 17) & 127], 1);
    __syncthreads();
    // ---- scan (threads 0..127, waves 0-1) ----
    int totv = 0, vv = 0;
    if (t < 128) {
        #pragma unroll
        for (int w = 0; w < 8; ++w) totv += c[w][t];
        vv = totv;
        #pragma unroll
        for (int o = 1; o < 64; o <<= 1) {
            int u = __shfl_up(vv, o, 64);
            if ((t & 63) >= o) vv += u;
        }
        if (t == 63) wsum = vv;
    }
    __syncthreads();
    if (t < 128) {
        if (t >= 64) vv += wsum;
        int rp = s0 + vv - totv;          // exclusive prefix
        float dv = rsqrtf((float)totv + 1.0f);   // +1 self loop
        sdinv[t] = dv;
        int node = b * 128 + t;
        if (node < N) {
            rcp[node]  = make_int2(rp, totv);
            dinv[node] = dv;
        }
        int run = rp;
        #pragma unroll
        for (int w = 0; w < 8; ++w) { cur[w][t] = run; run += c[w][t]; }
    }
    __syncthreads();
    // ---- per-wave cursor scatter, uint4 streaming (same index mapping) ----
    for (int i = t; i < nv4; i += 512) {
        uint4 v = tmp4[i];
        int q0 = atomicAdd(&cur[wv][(v.x >> 17) & 127], 1);
        csrc[q0] = (int)(v.x & 0x1FFFFu);
        int q1 = atomicAdd(&cur[wv][(v.y >> 17) & 127], 1);
        csrc[q1] = (int)(v.y & 0x1FFFFu);
        int q2 = atomicAdd(&cur[wv][(v.z >> 17) & 127], 1);
        csrc[q2] = (int)(v.z & 0x1FFFFu);
        int q3 = atomicAdd(&cur[wv][(v.w >> 17) & 127], 1);
        csrc[q3] = (int)(v.w & 0x1FFFFu);
    }
    if (t < rem) {
        unsigned int p = tmp[s0 + nv4 * 4 + t];
        int q = atomicAdd(&cur[wv][(p >> 17) & 127], 1);
        csrc[q] = (int)(p & 0x1FFFFu);
    }
    __syncthreads();
    // ---------------- fused xform1 MFMA tail (1 tile per wave) ------------
    int lane = t & 63, wid = t >> 6;
    int r16 = lane & 15, kg = lane >> 4;
    half8 bf[4][4];                       // [coltile][ktile]
    #pragma unroll
    for (int ct = 0; ct < 4; ++ct)
        #pragma unroll
        for (int kt = 0; kt < 4; ++kt)
            bf[ct][kt] = *(const half8*)&W1fr[(ct * 4 + kt) * 64 + lane];
    int v0 = b * 128 + wid * 16;
    int rowA = min(v0 + r16, N - 1);
    const float* xp = x + (size_t)rowA * 128 + kg * 8;
    half8 af[4];
    #pragma unroll
    for (int kt = 0; kt < 4; ++kt) {
        float4 p = *(const float4*)(xp + kt * 32);
        float4 q = *(const float4*)(xp + kt * 32 + 4);
        half8 a;
        a[0] = (_Float16)p.x; a[1] = (_Float16)p.y;
        a[2] = (_Float16)p.z; a[3] = (_Float16)p.w;
        a[4] = (_Float16)q.x; a[5] = (_Float16)q.y;
        a[6] = (_Float16)q.z; a[7] = (_Float16)q.w;
        af[kt] = a;
    }
    f32x4 acc0 = {0,0,0,0}, acc1 = {0,0,0,0}, acc2 = {0,0,0,0}, acc3 = {0,0,0,0};
    #pragma unroll
    for (int kt = 0; kt < 4; ++kt) {
        acc0 = __builtin_amdgcn_mfma_f32_16x16x32_f16(af[kt], bf[0][kt], acc0, 0, 0, 0);
        acc1 = __builtin_amdgcn_mfma_f32_16x16x32_f16(af[kt], bf[1][kt], acc1, 0, 0, 0);
        acc2 = __builtin_amdgcn_mfma_f32_16x16x32_f16(af[kt], bf[2][kt], acc2, 0, 0, 0);
        acc3 = __builtin_amdgcn_mfma_f32_16x16x32_f16(af[kt], bf[3][kt], acc3, 0, 0, 0);
    }
    #pragma unroll
    for (int r = 0; r < 4; ++r) {
        int nd = v0 + kg * 4 + r;
        if (nd < N) {
            float d = sdinv[wid * 16 + kg * 4 + r];
            int pk = __builtin_amdgcn_cvt_pk_fp8_f32(d * acc0[r], d * acc1[r], 0, false);
            pk     = __builtin_amdgcn_cvt_pk_fp8_f32(d * acc2[r], d * acc3[r], pk, true);
            hs[((size_t)nd << 4) + r16] = (unsigned int)pk;
        }
    }
}

// --- one wave per node, 4 lane-groups of 16; uniform main + masked tail ----
// fp8 row = 16 uints; byte b of uint s = channel s + 16*b.
__global__ __launch_bounds__(256) void k_agg(const int2* __restrict__ rcp,
        const int* __restrict__ csrc, const unsigned int* __restrict__ hp,
        float* __restrict__ acc, int N) {
    int w = (blockIdx.x * 256 + threadIdx.x) >> 6;
    int lane = threadIdx.x & 63;
    if (w >= N) return;
    int grp = lane >> 4, sub = lane & 15;
    int2 rc = rcp[w];
    int rs = rc.x, re = rc.x + rc.y;
    f32x2 A = {0.f, 0.f}, B = {0.f, 0.f};   // {sub, sub+16}, {sub+32, sub+48}
    if (grp == 0) {                                     // self loop, once
        unsigned v = hp[((size_t)w << 4) + sub];
        A = __builtin_amdgcn_cvt_pk_f32_fp8((int)v, false);
        B = __builtin_amdgcn_cvt_pk_f32_fp8((int)v, true);
    }
    int eb = rs;
    for (; eb + 32 <= re; eb += 32) {       // wave-uniform, no masks
        int e = eb + grp;
        int u0 = csrc[e];      int u1 = csrc[e + 4];
        int u2 = csrc[e + 8];  int u3 = csrc[e + 12];
        int u4 = csrc[e + 16]; int u5 = csrc[e + 20];
        int u6 = csrc[e + 24]; int u7 = csrc[e + 28];
        unsigned v0 = hp[((size_t)u0 << 4) + sub];
        unsigned v1 = hp[((size_t)u1 << 4) + sub];
        unsigned v2 = hp[((size_t)u2 << 4) + sub];
        unsigned v3 = hp[((size_t)u3 << 4) + sub];
        unsigned v4 = hp[((size_t)u4 << 4) + sub];
        unsigned v5 = hp[((size_t)u5 << 4) + sub];
        unsigned v6 = hp[((size_t)u6 << 4) + sub];
        unsigned v7 = hp[((size_t)u7 << 4) + sub];
        A += __builtin_amdgcn_cvt_pk_f32_fp8((int)v0, false);
        B += __builtin_amdgcn_cvt_pk_f32_fp8((int)v0, true);
        A += __builtin_amdgcn_cvt_pk_f32_fp8((int)v1, false);
        B += __builtin_amdgcn_cvt_pk_f32_fp8((int)v1, true);
        A += __builtin_amdgcn_cvt_pk_f32_fp8((int)v2, false);
        B += __builtin_amdgcn_cvt_pk_f32_fp8((int)v2, true);
        A += __builtin_amdgcn_cvt_pk_f32_fp8((int)v3, false);
        B += __builtin_amdgcn_cvt_pk_f32_fp8((int)v3, true);
        A += __builtin_amdgcn_cvt_pk_f32_fp8((int)v4, false);
        B += __builtin_amdgcn_cvt_pk_f32_fp8((int)v4, true);
        A += __builtin_amdgcn_cvt_pk_f32_fp8((int)v5, false);
        B += __builtin_amdgcn_cvt_pk_f32_fp8((int)v5, true);
        A += __builtin_amdgcn_cvt_pk_f32_fp8((int)v6, false);
        B += __builtin_amdgcn_cvt_pk_f32_fp8((int)v6, true);
        A += __builtin_amdgcn_cvt_pk_f32_fp8((int)v7, false);
        B += __builtin_amdgcn_cvt_pk_f32_fp8((int)v7, true);
    }
    int e = eb + grp;                       // masked tail, one iteration
    if (e < re) {
        int e1 = min(e + 4,  re - 1);
        int e2 = min(e + 8,  re - 1);
        int e3 = min(e + 12, re - 1);
        int e4 = min(e + 16, re - 1);
        int e5 = min(e + 20, re - 1);
        int e6 = min(e + 24, re - 1);
        int e7 = min(e + 28, re - 1);
        int u0 = csrc[e];
        int u1 = csrc[e1];
        int u2 = csrc[e2];
        int u3 = csrc[e3];
        int u4 = csrc[e4];
        int u5 = csrc[e5];
        int u6 = csrc[e6];
        int u7 = csrc[e7];
        unsigned v0 = hp[((size_t)u0 << 4) + sub];
        unsigned v1 = hp[((size_t)u1 << 4) + sub];
        unsigned v2 = hp[((size_t)u2 << 4) + sub];
        unsigned v3 = hp[((size_t)u3 << 4) + sub];
        unsigned v4 = hp[((size_t)u4 << 4) + sub];
        unsigned v5 = hp[((size_t)u5 << 4) + sub];
        unsigned v6 = hp[((size_t)u6 << 4) + sub];
        unsigned v7 = hp[((size_t)u7 << 4) + sub];
        float m1 = (e + 4  < re) ? 1.f : 0.f;
        float m2 = (e + 8  < re) ? 1.f : 0.f;
        float m3 = (e + 12 < re) ? 1.f : 0.f;
        float m4 = (e + 16 < re) ? 1.f : 0.f;
        float m5 = (e + 20 < re) ? 1.f : 0.f;
        float m6 = (e + 24 < re) ? 1.f : 0.f;
        float m7 = (e + 28 < re) ? 1.f : 0.f;
        A += __builtin_amdgcn_cvt_pk_f32_fp8((int)v0, false);
        B += __builtin_amdgcn_cvt_pk_f32_fp8((int)v0, true);
        f32x2 M1 = {m1, m1}, M2 = {m2, m2}, M3 = {m3, m3};
        f32x2 M4 = {m4, m4}, M5 = {m5, m5}, M6 = {m6, m6}, M7 = {m7, m7};
        A += M1 * __builtin_amdgcn_cvt_pk_f32_fp8((int)v1, false);
        B += M1 * __builtin_amdgcn_cvt_pk_f32_fp8((int)v1, true);
        A += M2 * __builtin_amdgcn_cvt_pk_f32_fp8((int)v2, false);
        B += M2 * __builtin_amdgcn_cvt_pk_f32_fp8((int)v2, true);
        A += M3 * __builtin_amdgcn_cvt_pk_f32_fp8((int)v3, false);
        B += M3 * __builtin_amdgcn_cvt_pk_f32_fp8((int)v3, true);
        A += M4 * __builtin_amdgcn_cvt_pk_f32_fp8((int)v4, false);
        B += M4 * __builtin_amdgcn_cvt_pk_f32_fp8((int)v4, true);
        A += M5 * __builtin_amdgcn_cvt_pk_f32_fp8((int)v5, false);
        B += M5 * __builtin_amdgcn_cvt_pk_f32_fp8((int)v5, true);
        A += M6 * __builtin_amdgcn_cvt_pk_f32_fp8((int)v6, false);
        B += M6 * __builtin_amdgcn_cvt_pk_f32_fp8((int)v6, true);
        A += M7 * __builtin_amdgcn_cvt_pk_f32_fp8((int)v7, false);
        B += M7 * __builtin_amdgcn_cvt_pk_f32_fp8((int)v7, true);
    }
    float a0 = A[0], a1 = A[1], a2 = B[0], a3 = B[1];
    a0 += __shfl_xor(a0, 16, 64); a0 += __shfl_xor(a0, 32, 64);
    a1 += __shfl_xor(a1, 16, 64); a1 += __shfl_xor(a1, 32, 64);
    a2 += __shfl_xor(a2, 16, 64); a2 += __shfl_xor(a2, 32, 64);
    a3 += __shfl_xor(a3, 16, 64); a3 += __shfl_xor(a3, 32, 64);
    if (grp == 0) {
        float* op = acc + ((size_t)w << 6) + sub;
        op[0]  = a0;
        op[16] = a1;
        op[32] = a2;
        op[48] = a3;
    }
}

// a = relu(dinv*acc + b1); hs2 = fp8(dinv * (a @ W2)) via MFMA; frag preload
__global__ __launch_bounds__(256) void k_xform2(const float* __restrict__ acc_in,
        const uint4* __restrict__ W2fr, const float* __restrict__ b1,
        const float* __restrict__ dinv, unsigned int* __restrict__ hs2, int N, int ntiles) {
    int t = threadIdx.x;
    int lane = t & 63, wid = t >> 6;
    int r16 = lane & 15, kg = lane >> 4;
    half8 bf[4][2];
    #pragma unroll
    for (int ct = 0; ct < 4; ++ct)
        #pragma unroll
        for (int kt = 0; kt < 2; ++kt)
            bf[ct][kt] = *(const half8*)&W2fr[(ct * 2 + kt) * 64 + lane];
    float b1r[2][8];
    #pragma unroll
    for (int kt = 0; kt < 2; ++kt)
        #pragma unroll
        for (int j = 0; j < 8; ++j) b1r[kt][j] = b1[kt * 32 + kg * 8 + j];
    int wtile = blockIdx.x * 4 + wid;
    int nw = gridDim.x * 4;
    for (int tile = wtile; tile < ntiles; tile += nw) {
        int v0 = tile * 16;
        int rowA = min(v0 + r16, N - 1);
        float da = dinv[rowA];
        const float* ap = acc_in + ((size_t)rowA << 6) + kg * 8;
        half8 af[2];
        #pragma unroll
        for (int kt = 0; kt < 2; ++kt) {
            float4 p = *(const float4*)(ap + kt * 32);
            float4 q = *(const float4*)(ap + kt * 32 + 4);
            half8 a;
            a[0] = (_Float16)fmaxf(fmaf(da, p.x, b1r[kt][0]), 0.f);
            a[1] = (_Float16)fmaxf(fmaf(da, p.y, b1r[kt][1]), 0.f);
            a[2] = (_Float16)fmaxf(fmaf(da, p.z, b1r[kt][2]), 0.f);
            a[3] = (_Float16)fmaxf(fmaf(da, p.w, b1r[kt][3]), 0.f);
            a[4] = (_Float16)fmaxf(fmaf(da, q.x, b1r[kt][4]), 0.f);
            a[5] = (_Float16)fmaxf(fmaf(da, q.y, b1r[kt][5]), 0.f);
            a[6] = (_Float16)fmaxf(fmaf(da, q.z, b1r[kt][6]), 0.f);
            a[7] = (_Float16)fmaxf(fmaf(da, q.w, b1r[kt][7]), 0.f);
            af[kt] = a;
        }
        f32x4 acc0 = {0,0,0,0}, acc1 = {0,0,0,0}, acc2 = {0,0,0,0}, acc3 = {0,0,0,0};
        #pragma unroll
        for (int kt = 0; kt < 2; ++kt) {
            acc0 = __builtin_amdgcn_mfma_f32_16x16x32_f16(af[kt], bf[0][kt], acc0, 0, 0, 0);
            acc1 = __builtin_amdgcn_mfma_f32_16x16x32_f16(af[kt], bf[1][kt], acc1, 0, 0, 0);
            acc2 = __builtin_amdgcn_mfma_f32_16x16x32_f16(af[kt], bf[2][kt], acc2, 0, 0, 0);
            acc3 = __builtin_amdgcn_mfma_f32_16x16x32_f16(af[kt], bf[3][kt], acc3, 0, 0, 0);
        }
        #pragma unroll
        for (int r = 0; r < 4; ++r) {
            int node = v0 + kg * 4 + r;
            if (node < N) {
                float d = dinv[node];
                int pk = __builtin_amdgcn_cvt_pk_fp8_f32(d * acc0[r], d * acc1[r], 0, false);
                pk     = __builtin_amdgcn_cvt_pk_fp8_f32(d * acc2[r], d * acc3[r], pk, true);
                hs2[((size_t)node << 4) + r16] = (unsigned int)pk;
            }
        }
    }
}

// a = relu(dinv*acc2 + b2); z = a @ Wf + bf; out = log_softmax(z); frag preload
__global__ __launch_bounds__(256) void k_final(const float* __restrict__ acc2,
        const uint4* __restrict__ Wffr, const float* __restrict__ b2,
        const float* __restrict__ bf, const float* __restrict__ dinv,
        float* __restrict__ out, int N, int ntiles) {
    int t = threadIdx.x;
    int lane = t & 63, wid = t >> 6;
    int r16 = lane & 15, kg = lane >> 4;
    half8 bfr[3][2];
    #pragma unroll
    for (int ct = 0; ct < 3; ++ct)
        #pragma unroll
        for (int kt = 0; kt < 2; ++kt)
            bfr[ct][kt] = *(const half8*)&Wffr[(ct * 2 + kt) * 64 + lane];
    float b2r[2][8];
    #pragma unroll
    for (int kt = 0; kt < 2; ++kt)
        #pragma unroll
        for (int j = 0; j < 8; ++j) b2r[kt][j] = b2[kt * 32 + kg * 8 + j];
    float bf0 = bf[r16];
    float bf1 = bf[16 + r16];
    float bf2 = (r16 < 8) ? bf[32 + r16] : 0.f;
    int wtile = blockIdx.x * 4 + wid;
    int nw = gridDim.x * 4;
    for (int tile = wtile; tile < ntiles; tile += nw) {
        int v0 = tile * 16;
        int rowA = min(v0 + r16, N - 1);
        float da = dinv[rowA];
        const float* ap = acc2 + ((size_t)rowA << 6) + kg * 8;
        half8 af[2];
        #pragma unroll
        for (int kt = 0; kt < 2; ++kt) {
            float4 p = *(const float4*)(ap + kt * 32);
            float4 q = *(const float4*)(ap + kt * 32 + 4);
            half8 a;
            a[0] = (_Float16)fmaxf(fmaf(da, p.x, b2r[kt][0]), 0.f);
            a[1] = (_Float16)fmaxf(fmaf(da, p.y, b2r[kt][1]), 0.f);
            a[2] = (_Float16)fmaxf(fmaf(da, p.z, b2r[kt][2]), 0.f);
            a[3] = (_Float16)fmaxf(fmaf(da, p.w, b2r[kt][3]), 0.f);
            a[4] = (_Float16)fmaxf(fmaf(da, q.x, b2r[kt][4]), 0.f);
            a[5] = (_Float16)fmaxf(fmaf(da, q.y, b2r[kt][5]), 0.f);
            a[6] = (_Float16)fmaxf(fmaf(da, q.z, b2r[kt][6]), 0.f);
            a[7] = (_Float16)fmaxf(fmaf(da, q.w, b2r[kt][7]), 0.f);
            af[kt] = a;
        }
        f32x4 a0 = {0,0,0,0}, a1 = {0,0,0,0}, a2 = {0,0,0,0};
        #pragma unroll
        for (int kt = 0; kt < 2; ++kt) {
            a0 = __builtin_amdgcn_mfma_f32_16x16x32_f16(af[kt], bfr[0][kt], a0, 0, 0, 0);
            a1 = __builtin_amdgcn_mfma_f32_16x16x32_f16(af[kt], bfr[1][kt], a1, 0, 0, 0);
            a2 = __builtin_amdgcn_mfma_f32_16x16x32_f16(af[kt], bfr[2][kt], a2, 0, 0, 0);
        }
        #pragma unroll
        for (int r = 0; r < 4; ++r) {
            float z0 = a0[r] + bf0;
            float z1 = a1[r] + bf1;
            float z2 = (r16 < 8) ? (a2[r] + bf2) : -INFINITY;
            float m = fmaxf(fmaxf(z0, z1), z2);
            #pragma unroll
            for (int o = 8; o; o >>= 1) m = fmaxf(m, __shfl_xor(m, o, 64));
            float s = expf(z0 - m) + expf(z1 - m) + ((r16 < 8) ? expf(z2 - m) : 0.f);
            #pragma unroll
            for (int o = 8; o; o >>= 1) s += __shfl_xor(s, o, 64);
            float ls = m + logf(s);
            int node = v0 + kg * 4 + r;
            if (node < N) {
                float* op = out + (size_t)node * 40;
                op[r16]      = z0 - ls;
                op[16 + r16] = z1 - ls;
                if (r16 < 8) op[32 + r16] = z2 - ls;
            }
        }
    }
}

extern "C" void kernel_launch(void* const* d_in, const int* in_sizes, int n_in,
                              void* d_out, int out_size, void* d_ws, size_t ws_size,
                              hipStream_t stream) {
    const float* x  = (const float*)d_in[0];
    const int*   ei = (const int*)d_in[1];   // [2, E]: row 0 = src, row 1 = dst
    const float* W1 = (const float*)d_in[2];
    const float* b1 = (const float*)d_in[3];
    const float* W2 = (const float*)d_in[4];
    const float* b2 = (const float*)d_in[5];
    const float* Wf = (const float*)d_in[6];
    const float* bf = (const float*)d_in[7];
    float* out = (float*)d_out;

    const int N = in_sizes[0] / 128;
    const int E = in_sizes[1] / 2;
    const int* src = ei;
    const int* dst = ei + E;
    const int NB = (N + 127) >> BSH;         // 128-node buckets (<=1024)

    auto align = [](size_t s) { return (s + 255) & ~(size_t)255; };
    char* ws = (char*)d_ws;
    size_t o = 0;
    int2*  rcp     = (int2*)(ws + o);  o += align((size_t)N * 8);
    float* dinv    = (float*)(ws + o); o += align((size_t)N * 4);
    int*   cursor1 = (int*)(ws + o);   o += align(1024 * 4);
    uint4* W1fr    = (uint4*)(ws + o); o += align(16 * 64 * 16);
    uint4* W2fr    = (uint4*)(ws + o); o += align(8 * 64 * 16);
    uint4* Wffr    = (uint4*)(ws + o); o += align(6 * 64 * 16);
    int*   csrc    = (int*)(ws + o);   o += align((size_t)NB * CAP * 4);
    unsigned int* B1 = (unsigned int*)(ws + o); o += align((size_t)N * 64);  // hs fp8
    float*  B2     = (float*)(ws + o);  o += align((size_t)N * 64 * 4);      // acc
    unsigned int* tmp = (unsigned int*)B2;   // alias: tmp dead before k_agg writes B2

    int blkT  = (E + T1 - 1) / T1;
    int ntile = (N + 15) / 16;
    int gX = 512;                     // persistent MFMA blocks (4 waves each)

    k_prep <<<1,   1024, 0, stream>>>(W1, W2, Wf, cursor1, W1fr, W2fr, Wffr, NB);
    k_pass1<<<blkT, 256, 0, stream>>>(src, dst, cursor1, tmp, E, NB);
    k_p2x  <<<NB,   512, 0, stream>>>(tmp, cursor1, rcp, csrc, dinv, x, W1fr, B1, N);

    int blkAgg = (N * 64 + 255) / 256;  // one wave per node
    k_agg   <<<blkAgg, 256, 0, stream>>>(rcp, csrc, B1, B2, N);
    k_xform2<<<gX, 256, 0, stream>>>(B2, W2fr, b1, dinv, B1, N, ntile);
    k_agg   <<<blkAgg, 256, 0, stream>>>(rcp, csrc, B1, B2, N);
    k_final <<<gX, 256, 0, stream>>>(B2, Wffr, b2, bf, dinv, out, N, ntile);
}

// Round 21
// 185.027 us; speedup vs baseline: 1.1161x; 1.0253x over previous
//
#include <hip/hip_runtime.h>
#include <hip/hip_fp16.h>
#include <cstdint>
#include <cstddef>
#include <cmath>

// ---------------------------------------------------------------------------
// GCN via CSR aggregation:
//   k_prep: cursor init + precompute W1/W2/Wf MFMA fragments (fp16 frag arrays)
//   binning: fixed-capacity dst-buckets (128 nodes, CAP=6144) -> k_pass1
//            (uint4 edge loads, 3-sync two-level scan) packs edges into tmp
//            runs -> k_p2x (512 thr): per-wave LDS histograms (uint4 stream)
//            -> 2-wave shfl scan -> rcp/dinv -> per-wave cursor scatter ->
//            fused xform1 MFMA tail (1 tile/wave).
//   agg: one wave per node, 4 lane-groups of 16, fp8 rows; unroll-8,
//        wave-uniform main loop (packed f32x2 adds) + single predicated tail.
//   xform2/final: MFMA 16x16x32 f16 persistent blocks, fp8 pack/unpack via
//   v_cvt_pk_fp8_f32 / v_cvt_pk_f32_fp8 (byte b of uint s = channel s+16b).
//   tmp aliases B2 (dead before first k_agg write).
// ---------------------------------------------------------------------------

#define T1  4096    // edges per pass-1 tile
#define BSH 7       // 128-node buckets
#define CAP 6144    // bucket capacity (avg 4092, sigma ~64); divisible by 4

typedef _Float16 half8 __attribute__((ext_vector_type(8)));
typedef float f32x4 __attribute__((ext_vector_type(4)));
typedef float f32x2 __attribute__((ext_vector_type(2)));

// cursor init + weight-fragment precompute (one block)
__global__ __launch_bounds__(1024) void k_prep(const float* __restrict__ W1,
        const float* __restrict__ W2, const float* __restrict__ Wf,
        int* __restrict__ cursor1, uint4* __restrict__ W1fr,
        uint4* __restrict__ W2fr, uint4* __restrict__ Wffr, int NB) {
    int t = threadIdx.x;
    for (int i = t; i < NB; i += 1024) cursor1[i] = i * CAP;
    if (t < 64) {
        int r16 = t & 15, kg = t >> 4;
        #pragma unroll
        for (int ct = 0; ct < 4; ++ct)
            #pragma unroll
            for (int kt = 0; kt < 4; ++kt) {
                half8 h;
                #pragma unroll
                for (int j = 0; j < 8; ++j)
                    h[j] = (_Float16)W1[(kt * 32 + kg * 8 + j) * 64 + ct * 16 + r16];
                W1fr[(ct * 4 + kt) * 64 + t] = *(uint4*)&h;
            }
        #pragma unroll
        for (int ct = 0; ct < 4; ++ct)
            #pragma unroll
            for (int kt = 0; kt < 2; ++kt) {
                half8 h;
                #pragma unroll
                for (int j = 0; j < 8; ++j)
                    h[j] = (_Float16)W2[(kt * 32 + kg * 8 + j) * 64 + ct * 16 + r16];
                W2fr[(ct * 2 + kt) * 64 + t] = *(uint4*)&h;
            }
        #pragma unroll
        for (int ct = 0; ct < 3; ++ct)
            #pragma unroll
            for (int kt = 0; kt < 2; ++kt) {
                int col = ct * 16 + r16;
                half8 h;
                #pragma unroll
                for (int j = 0; j < 8; ++j)
                    h[j] = (col < 40) ? (_Float16)Wf[(kt * 32 + kg * 8 + j) * 40 + col]
                                      : (_Float16)0.f;
                Wffr[(ct * 2 + kt) * 64 + t] = *(uint4*)&h;
            }
    }
}

// uint4 edge loads + two-level scan (3 barriers for the scan phase)
__global__ __launch_bounds__(256) void k_pass1(const int* __restrict__ src,
        const int* __restrict__ dst, int* __restrict__ cursor1,
        unsigned int* __restrict__ tmp, int E, int NB) {
    __shared__ unsigned int pack[T1];                 // 16 KB
    __shared__ unsigned short bkt[T1];                //  8 KB
    __shared__ int h[1024], hs_[1024], gbase[1024];   // 12 KB
    __shared__ int wtot[4];
    int t = threadIdx.x;
    for (int i = t; i < 1024; i += 256) h[i] = 0;
    __syncthreads();
    int base = blockIdx.x * T1;
    int n = min(T1, E - base);
    int nv4 = n >> 2, rem = n & 3;
    unsigned int pk[16];
    int bl[16];
    #pragma unroll
    for (int i = 0; i < 4; ++i) {
        int g = i * 256 + t;                 // 4-edge group index
        if (g < nv4) {
            int4 s4 = ((const int4*)(src + base))[g];
            int4 d4 = ((const int4*)(dst + base))[g];
            int b0 = d4.x >> BSH;
            pk[4*i]   = (unsigned)s4.x | ((unsigned)(d4.x & 127) << 17);
            bl[4*i]   = (b0 << 13) | atomicAdd(&h[b0], 1);
            int b1 = d4.y >> BSH;
            pk[4*i+1] = (unsigned)s4.y | ((unsigned)(d4.y & 127) << 17);
            bl[4*i+1] = (b1 << 13) | atomicAdd(&h[b1], 1);
            int b2 = d4.z >> BSH;
            pk[4*i+2] = (unsigned)s4.z | ((unsigned)(d4.z & 127) << 17);
            bl[4*i+2] = (b2 << 13) | atomicAdd(&h[b2], 1);
            int b3 = d4.w >> BSH;
            pk[4*i+3] = (unsigned)s4.w | ((unsigned)(d4.w & 127) << 17);
            bl[4*i+3] = (b3 << 13) | atomicAdd(&h[b3], 1);
        } else {
            bl[4*i] = bl[4*i+1] = bl[4*i+2] = bl[4*i+3] = -1;
        }
    }
    unsigned int pk_r = 0; int bl_r = -1;     // scalar remainder (rem<4)
    if (t < rem) {
        int idx = nv4 * 4 + t;
        int s_ = src[base + idx], d = dst[base + idx];
        int b = d >> BSH;
        pk_r = (unsigned)s_ | ((unsigned)(d & 127) << 17);
        bl_r = (b << 13) | atomicAdd(&h[b], 1);
    }
    __syncthreads();
    // ---- two-level inclusive scan of h into hs_ (3 barriers incl. above) --
    {
        int b0 = 4 * t;
        int e0 = h[b0], e1 = h[b0+1], e2 = h[b0+2], e3 = h[b0+3];
        int s1 = e0 + e1, s2 = s1 + e2, s3 = s2 + e3;
        int lane = t & 63, wv = t >> 6;
        int vv = s3;
        #pragma unroll
        for (int o = 1; o < 64; o <<= 1) {
            int u = __shfl_up(vv, o, 64);
            if (lane >= o) vv += u;
        }
        if (lane == 63) wtot[wv] = vv;
        __syncthreads();
        int off = 0;
        #pragma unroll
        for (int w = 0; w < 4; ++w) off += (w < wv) ? wtot[w] : 0;
        int excl = off + vv - s3;            // edges before entry 4t
        hs_[b0]   = excl + e0;
        hs_[b0+1] = excl + s1;
        hs_[b0+2] = excl + s2;
        hs_[b0+3] = excl + s3;
    }
    __syncthreads();
    for (int i = t; i < NB; i += 256)
        gbase[i] = h[i] ? atomicAdd(&cursor1[i], h[i]) : 0;
    __syncthreads();
    #pragma unroll
    for (int i = 0; i < 16; ++i) {
        if (bl[i] >= 0) {
            int b = bl[i] >> 13, lo = bl[i] & 8191;
            int slot = hs_[b] - h[b] + lo;
            pack[slot] = pk[i];
            bkt[slot]  = (unsigned short)b;
        }
    }
    if (bl_r >= 0) {
        int b = bl_r >> 13, lo = bl_r & 8191;
        int slot = hs_[b] - h[b] + lo;
        pack[slot] = pk_r;
        bkt[slot]  = (unsigned short)b;
    }
    __syncthreads();
    for (int s_ = t; s_ < n; s_ += 256) {
        int b = bkt[s_];
        tmp[gbase[b] + (s_ - (hs_[b] - h[b]))] = pack[s_];
    }
}

// per-bucket (128 nodes), 512 threads / 8 waves:
// per-wave uint4 histogram -> 2-wave shfl scan -> rcp/dinv ->
// per-wave cursor scatter -> fused xform1 MFMA tail (1 tile per wave).
__global__ __launch_bounds__(512) void k_p2x(const unsigned int* __restrict__ tmp,
        const int* __restrict__ cursor1, int2* __restrict__ rcp,
        int* __restrict__ csrc, float* __restrict__ dinv,
        const float* __restrict__ x, const uint4* __restrict__ W1fr,
        unsigned int* __restrict__ hs, int N) {
    __shared__ int c[8][128], cur[8][128];    // 8 KB
    __shared__ float sdinv[128];
    __shared__ int wsum;
    int t = threadIdx.x, b = blockIdx.x;
    int wv = t >> 6;
    for (int i = t; i < 1024; i += 512) ((int*)c)[i] = 0;
    __syncthreads();
    int s0 = b * CAP, s1 = cursor1[b];
    int n = s1 - s0;
    int nv4 = n >> 2, rem = n & 3;
    const uint4* tmp4 = (const uint4*)(tmp + s0);
    for (int i = t; i < nv4; i += 512) {
        uint4 v = tmp4[i];
        atomicAdd(&c[wv][(v.x >> 17) & 127], 1);
        atomicAdd(&c[wv][(v.y >> 17) & 127], 1);
        atomicAdd(&c[wv][(v.z >> 17) & 127], 1);
        atomicAdd(&c[wv][(v.w >> 17) & 127], 1);
    }
    if (t < rem)
        atomicAdd(&c[wv][(tmp[s0 + nv4 * 4 + t] >> 17) & 127], 1);
    __syncthreads();
    int totv = 0, vv = 0;
    if (t < 128) {
        #pragma unroll
        for (int w = 0; w < 8; ++w) totv += c[w][t];
        vv = totv;
        #pragma unroll
        for (int o = 1; o < 64; o <<= 1) {
            int u = __shfl_up(vv, o, 64);
            if ((t & 63) >= o) vv += u;
        }
        if (t == 63) wsum = vv;
    }
    __syncthreads();
    if (t < 128) {
        if (t >= 64) vv += wsum;
        int rp = s0 + vv - totv;          // exclusive prefix
        float dv = rsqrtf((float)totv + 1.0f);   // +1 self loop
        sdinv[t] = dv;
        int node = b * 128 + t;
        if (node < N) {
            rcp[node]  = make_int2(rp, totv);
            dinv[node] = dv;
        }
        int run = rp;
        #pragma unroll
        for (int w = 0; w < 8; ++w) { cur[w][t] = run; run += c[w][t]; }
    }
    __syncthreads();
    for (int i = t; i < nv4; i += 512) {
        uint4 v = tmp4[i];
        int q0 = atomicAdd(&cur[wv][(v.x >> 17) & 127], 1);
        csrc[q0] = (int)(v.x & 0x1FFFFu);
        int q1 = atomicAdd(&cur[wv][(v.y >> 17) & 127], 1);
        csrc[q1] = (int)(v.y & 0x1FFFFu);
        int q2 = atomicAdd(&cur[wv][(v.z >> 17) & 127], 1);
        csrc[q2] = (int)(v.z & 0x1FFFFu);
        int q3 = atomicAdd(&cur[wv][(v.w >> 17) & 127], 1);
        csrc[q3] = (int)(v.w & 0x1FFFFu);
    }
    if (t < rem) {
        unsigned int p = tmp[s0 + nv4 * 4 + t];
        int q = atomicAdd(&cur[wv][(p >> 17) & 127], 1);
        csrc[q] = (int)(p & 0x1FFFFu);
    }
    __syncthreads();
    // ---------------- fused xform1 MFMA tail (1 tile per wave) ------------
    int lane = t & 63, wid = t >> 6;
    int r16 = lane & 15, kg = lane >> 4;
    half8 bf[4][4];                       // [coltile][ktile]
    #pragma unroll
    for (int ct = 0; ct < 4; ++ct)
        #pragma unroll
        for (int kt = 0; kt < 4; ++kt)
            bf[ct][kt] = *(const half8*)&W1fr[(ct * 4 + kt) * 64 + lane];
    int v0 = b * 128 + wid * 16;
    int rowA = min(v0 + r16, N - 1);
    const float* xp = x + (size_t)rowA * 128 + kg * 8;
    half8 af[4];
    #pragma unroll
    for (int kt = 0; kt < 4; ++kt) {
        float4 p = *(const float4*)(xp + kt * 32);
        float4 q = *(const float4*)(xp + kt * 32 + 4);
        half8 a;
        a[0] = (_Float16)p.x; a[1] = (_Float16)p.y;
        a[2] = (_Float16)p.z; a[3] = (_Float16)p.w;
        a[4] = (_Float16)q.x; a[5] = (_Float16)q.y;
        a[6] = (_Float16)q.z; a[7] = (_Float16)q.w;
        af[kt] = a;
    }
    f32x4 acc0 = {0,0,0,0}, acc1 = {0,0,0,0}, acc2 = {0,0,0,0}, acc3 = {0,0,0,0};
    #pragma unroll
    for (int kt = 0; kt < 4; ++kt) {
        acc0 = __builtin_amdgcn_mfma_f32_16x16x32_f16(af[kt], bf[0][kt], acc0, 0, 0, 0);
        acc1 = __builtin_amdgcn_mfma_f32_16x16x32_f16(af[kt], bf[1][kt], acc1, 0, 0, 0);
        acc2 = __builtin_amdgcn_mfma_f32_16x16x32_f16(af[kt], bf[2][kt], acc2, 0, 0, 0);
        acc3 = __builtin_amdgcn_mfma_f32_16x16x32_f16(af[kt], bf[3][kt], acc3, 0, 0, 0);
    }
    #pragma unroll
    for (int r = 0; r < 4; ++r) {
        int nd = v0 + kg * 4 + r;
        if (nd < N) {
            float d = sdinv[wid * 16 + kg * 4 + r];
            int pk = __builtin_amdgcn_cvt_pk_fp8_f32(d * acc0[r], d * acc1[r], 0, false);
            pk     = __builtin_amdgcn_cvt_pk_fp8_f32(d * acc2[r], d * acc3[r], pk, true);
            hs[((size_t)nd << 4) + r16] = (unsigned int)pk;
        }
    }
}

// --- one wave per node, 4 lane-groups of 16; uniform main + masked tail ----
// fp8 row = 16 uints; byte b of uint s = channel s + 16*b.
__global__ __launch_bounds__(256) void k_agg(const int2* __restrict__ rcp,
        const int* __restrict__ csrc, const unsigned int* __restrict__ hp,
        float* __restrict__ acc, int N) {
    int w = (blockIdx.x * 256 + threadIdx.x) >> 6;
    int lane = threadIdx.x & 63;
    if (w >= N) return;
    int grp = lane >> 4, sub = lane & 15;
    int2 rc = rcp[w];
    int rs = rc.x, re = rc.x + rc.y;
    f32x2 A = {0.f, 0.f}, B = {0.f, 0.f};   // {sub, sub+16}, {sub+32, sub+48}
    if (grp == 0) {                                     // self loop, once
        unsigned v = hp[((size_t)w << 4) + sub];
        A = __builtin_amdgcn_cvt_pk_f32_fp8((int)v, false);
        B = __builtin_amdgcn_cvt_pk_f32_fp8((int)v, true);
    }
    int eb = rs;
    for (; eb + 32 <= re; eb += 32) {       // wave-uniform, no masks
        int e = eb + grp;
        int u0 = csrc[e];      int u1 = csrc[e + 4];
        int u2 = csrc[e + 8];  int u3 = csrc[e + 12];
        int u4 = csrc[e + 16]; int u5 = csrc[e + 20];
        int u6 = csrc[e + 24]; int u7 = csrc[e + 28];
        unsigned v0 = hp[((size_t)u0 << 4) + sub];
        unsigned v1 = hp[((size_t)u1 << 4) + sub];
        unsigned v2 = hp[((size_t)u2 << 4) + sub];
        unsigned v3 = hp[((size_t)u3 << 4) + sub];
        unsigned v4 = hp[((size_t)u4 << 4) + sub];
        unsigned v5 = hp[((size_t)u5 << 4) + sub];
        unsigned v6 = hp[((size_t)u6 << 4) + sub];
        unsigned v7 = hp[((size_t)u7 << 4) + sub];
        A += __builtin_amdgcn_cvt_pk_f32_fp8((int)v0, false);
        B += __builtin_amdgcn_cvt_pk_f32_fp8((int)v0, true);
        A += __builtin_amdgcn_cvt_pk_f32_fp8((int)v1, false);
        B += __builtin_amdgcn_cvt_pk_f32_fp8((int)v1, true);
        A += __builtin_amdgcn_cvt_pk_f32_fp8((int)v2, false);
        B += __builtin_amdgcn_cvt_pk_f32_fp8((int)v2, true);
        A += __builtin_amdgcn_cvt_pk_f32_fp8((int)v3, false);
        B += __builtin_amdgcn_cvt_pk_f32_fp8((int)v3, true);
        A += __builtin_amdgcn_cvt_pk_f32_fp8((int)v4, false);
        B += __builtin_amdgcn_cvt_pk_f32_fp8((int)v4, true);
        A += __builtin_amdgcn_cvt_pk_f32_fp8((int)v5, false);
        B += __builtin_amdgcn_cvt_pk_f32_fp8((int)v5, true);
        A += __builtin_amdgcn_cvt_pk_f32_fp8((int)v6, false);
        B += __builtin_amdgcn_cvt_pk_f32_fp8((int)v6, true);
        A += __builtin_amdgcn_cvt_pk_f32_fp8((int)v7, false);
        B += __builtin_amdgcn_cvt_pk_f32_fp8((int)v7, true);
    }
    int e = eb + grp;                       // masked tail, one iteration
    if (e < re) {
        int e1 = min(e + 4,  re - 1);
        int e2 = min(e + 8,  re - 1);
        int e3 = min(e + 12, re - 1);
        int e4 = min(e + 16, re - 1);
        int e5 = min(e + 20, re - 1);
        int e6 = min(e + 24, re - 1);
        int e7 = min(e + 28, re - 1);
        int u0 = csrc[e];
        int u1 = csrc[e1];
        int u2 = csrc[e2];
        int u3 = csrc[e3];
        int u4 = csrc[e4];
        int u5 = csrc[e5];
        int u6 = csrc[e6];
        int u7 = csrc[e7];
        unsigned v0 = hp[((size_t)u0 << 4) + sub];
        unsigned v1 = hp[((size_t)u1 << 4) + sub];
        unsigned v2 = hp[((size_t)u2 << 4) + sub];
        unsigned v3 = hp[((size_t)u3 << 4) + sub];
        unsigned v4 = hp[((size_t)u4 << 4) + sub];
        unsigned v5 = hp[((size_t)u5 << 4) + sub];
        unsigned v6 = hp[((size_t)u6 << 4) + sub];
        unsigned v7 = hp[((size_t)u7 << 4) + sub];
        float m1 = (e + 4  < re) ? 1.f : 0.f;
        float m2 = (e + 8  < re) ? 1.f : 0.f;
        float m3 = (e + 12 < re) ? 1.f : 0.f;
        float m4 = (e + 16 < re) ? 1.f : 0.f;
        float m5 = (e + 20 < re) ? 1.f : 0.f;
        float m6 = (e + 24 < re) ? 1.f : 0.f;
        float m7 = (e + 28 < re) ? 1.f : 0.f;
        A += __builtin_amdgcn_cvt_pk_f32_fp8((int)v0, false);
        B += __builtin_amdgcn_cvt_pk_f32_fp8((int)v0, true);
        f32x2 M1 = {m1, m1}, M2 = {m2, m2}, M3 = {m3, m3};
        f32x2 M4 = {m4, m4}, M5 = {m5, m5}, M6 = {m6, m6}, M7 = {m7, m7};
        A += M1 * __builtin_amdgcn_cvt_pk_f32_fp8((int)v1, false);
        B += M1 * __builtin_amdgcn_cvt_pk_f32_fp8((int)v1, true);
        A += M2 * __builtin_amdgcn_cvt_pk_f32_fp8((int)v2, false);
        B += M2 * __builtin_amdgcn_cvt_pk_f32_fp8((int)v2, true);
        A += M3 * __builtin_amdgcn_cvt_pk_f32_fp8((int)v3, false);
        B += M3 * __builtin_amdgcn_cvt_pk_f32_fp8((int)v3, true);
        A += M4 * __builtin_amdgcn_cvt_pk_f32_fp8((int)v4, false);
        B += M4 * __builtin_amdgcn_cvt_pk_f32_fp8((int)v4, true);
        A += M5 * __builtin_amdgcn_cvt_pk_f32_fp8((int)v5, false);
        B += M5 * __builtin_amdgcn_cvt_pk_f32_fp8((int)v5, true);
        A += M6 * __builtin_amdgcn_cvt_pk_f32_fp8((int)v6, false);
        B += M6 * __builtin_amdgcn_cvt_pk_f32_fp8((int)v6, true);
        A += M7 * __builtin_amdgcn_cvt_pk_f32_fp8((int)v7, false);
        B += M7 * __builtin_amdgcn_cvt_pk_f32_fp8((int)v7, true);
    }
    float a0 = A[0], a1 = A[1], a2 = B[0], a3 = B[1];
    a0 += __shfl_xor(a0, 16, 64); a0 += __shfl_xor(a0, 32, 64);
    a1 += __shfl_xor(a1, 16, 64); a1 += __shfl_xor(a1, 32, 64);
    a2 += __shfl_xor(a2, 16, 64); a2 += __shfl_xor(a2, 32, 64);
    a3 += __shfl_xor(a3, 16, 64); a3 += __shfl_xor(a3, 32, 64);
    if (grp == 0) {
        float* op = acc + ((size_t)w << 6) + sub;
        op[0]  = a0;
        op[16] = a1;
        op[32] = a2;
        op[48] = a3;
    }
}

// a = relu(dinv*acc + b1); hs2 = fp8(dinv * (a @ W2)) via MFMA; frag preload
__global__ __launch_bounds__(256) void k_xform2(const float* __restrict__ acc_in,
        const uint4* __restrict__ W2fr, const float* __restrict__ b1,
        const float* __restrict__ dinv, unsigned int* __restrict__ hs2, int N, int ntiles) {
    int t = threadIdx.x;
    int lane = t & 63, wid = t >> 6;
    int r16 = lane & 15, kg = lane >> 4;
    half8 bf[4][2];
    #pragma unroll
    for (int ct = 0; ct < 4; ++ct)
        #pragma unroll
        for (int kt = 0; kt < 2; ++kt)
            bf[ct][kt] = *(const half8*)&W2fr[(ct * 2 + kt) * 64 + lane];
    float b1r[2][8];
    #pragma unroll
    for (int kt = 0; kt < 2; ++kt)
        #pragma unroll
        for (int j = 0; j < 8; ++j) b1r[kt][j] = b1[kt * 32 + kg * 8 + j];
    int wtile = blockIdx.x * 4 + wid;
    int nw = gridDim.x * 4;
    for (int tile = wtile; tile < ntiles; tile += nw) {
        int v0 = tile * 16;
        int rowA = min(v0 + r16, N - 1);
        float da = dinv[rowA];
        const float* ap = acc_in + ((size_t)rowA << 6) + kg * 8;
        half8 af[2];
        #pragma unroll
        for (int kt = 0; kt < 2; ++kt) {
            float4 p = *(const float4*)(ap + kt * 32);
            float4 q = *(const float4*)(ap + kt * 32 + 4);
            half8 a;
            a[0] = (_Float16)fmaxf(fmaf(da, p.x, b1r[kt][0]), 0.f);
            a[1] = (_Float16)fmaxf(fmaf(da, p.y, b1r[kt][1]), 0.f);
            a[2] = (_Float16)fmaxf(fmaf(da, p.z, b1r[kt][2]), 0.f);
            a[3] = (_Float16)fmaxf(fmaf(da, p.w, b1r[kt][3]), 0.f);
            a[4] = (_Float16)fmaxf(fmaf(da, q.x, b1r[kt][4]), 0.f);
            a[5] = (_Float16)fmaxf(fmaf(da, q.y, b1r[kt][5]), 0.f);
            a[6] = (_Float16)fmaxf(fmaf(da, q.z, b1r[kt][6]), 0.f);
            a[7] = (_Float16)fmaxf(fmaf(da, q.w, b1r[kt][7]), 0.f);
            af[kt] = a;
        }
        f32x4 acc0 = {0,0,0,0}, acc1 = {0,0,0,0}, acc2 = {0,0,0,0}, acc3 = {0,0,0,0};
        #pragma unroll
        for (int kt = 0; kt < 2; ++kt) {
            acc0 = __builtin_amdgcn_mfma_f32_16x16x32_f16(af[kt], bf[0][kt], acc0, 0, 0, 0);
            acc1 = __builtin_amdgcn_mfma_f32_16x16x32_f16(af[kt], bf[1][kt], acc1, 0, 0, 0);
            acc2 = __builtin_amdgcn_mfma_f32_16x16x32_f16(af[kt], bf[2][kt], acc2, 0, 0, 0);
            acc3 = __builtin_amdgcn_mfma_f32_16x16x32_f16(af[kt], bf[3][kt], acc3, 0, 0, 0);
        }
        #pragma unroll
        for (int r = 0; r < 4; ++r) {
            int node = v0 + kg * 4 + r;
            if (node < N) {
                float d = dinv[node];
                int pk = __builtin_amdgcn_cvt_pk_fp8_f32(d * acc0[r], d * acc1[r], 0, false);
                pk     = __builtin_amdgcn_cvt_pk_fp8_f32(d * acc2[r], d * acc3[r], pk, true);
                hs2[((size_t)node << 4) + r16] = (unsigned int)pk;
            }
        }
    }
}

// a = relu(dinv*acc2 + b2); z = a @ Wf + bf; out = log_softmax(z); frag preload
__global__ __launch_bounds__(256) void k_final(const float* __restrict__ acc2,
        const uint4* __restrict__ Wffr, const float* __restrict__ b2,
        const float* __restrict__ bf, const float* __restrict__ dinv,
        float* __restrict__ out, int N, int ntiles) {
    int t = threadIdx.x;
    int lane = t & 63, wid = t >> 6;
    int r16 = lane & 15, kg = lane >> 4;
    half8 bfr[3][2];
    #pragma unroll
    for (int ct = 0; ct < 3; ++ct)
        #pragma unroll
        for (int kt = 0; kt < 2; ++kt)
            bfr[ct][kt] = *(const half8*)&Wffr[(ct * 2 + kt) * 64 + lane];
    float b2r[2][8];
    #pragma unroll
    for (int kt = 0; kt < 2; ++kt)
        #pragma unroll
        for (int j = 0; j < 8; ++j) b2r[kt][j] = b2[kt * 32 + kg * 8 + j];
    float bf0 = bf[r16];
    float bf1 = bf[16 + r16];
    float bf2 = (r16 < 8) ? bf[32 + r16] : 0.f;
    int wtile = blockIdx.x * 4 + wid;
    int nw = gridDim.x * 4;
    for (int tile = wtile; tile < ntiles; tile += nw) {
        int v0 = tile * 16;
        int rowA = min(v0 + r16, N - 1);
        float da = dinv[rowA];
        const float* ap = acc2 + ((size_t)rowA << 6) + kg * 8;
        half8 af[2];
        #pragma unroll
        for (int kt = 0; kt < 2; ++kt) {
            float4 p = *(const float4*)(ap + kt * 32);
            float4 q = *(const float4*)(ap + kt * 32 + 4);
            half8 a;
            a[0] = (_Float16)fmaxf(fmaf(da, p.x, b2r[kt][0]), 0.f);
            a[1] = (_Float16)fmaxf(fmaf(da, p.y, b2r[kt][1]), 0.f);
            a[2] = (_Float16)fmaxf(fmaf(da, p.z, b2r[kt][2]), 0.f);
            a[3] = (_Float16)fmaxf(fmaf(da, p.w, b2r[kt][3]), 0.f);
            a[4] = (_Float16)fmaxf(fmaf(da, q.x, b2r[kt][4]), 0.f);
            a[5] = (_Float16)fmaxf(fmaf(da, q.y, b2r[kt][5]), 0.f);
            a[6] = (_Float16)fmaxf(fmaf(da, q.z, b2r[kt][6]), 0.f);
            a[7] = (_Float16)fmaxf(fmaf(da, q.w, b2r[kt][7]), 0.f);
            af[kt] = a;
        }
        f32x4 a0 = {0,0,0,0}, a1 = {0,0,0,0}, a2 = {0,0,0,0};
        #pragma unroll
        for (int kt = 0; kt < 2; ++kt) {
            a0 = __builtin_amdgcn_mfma_f32_16x16x32_f16(af[kt], bfr[0][kt], a0, 0, 0, 0);
            a1 = __builtin_amdgcn_mfma_f32_16x16x32_f16(af[kt], bfr[1][kt], a1, 0, 0, 0);
            a2 = __builtin_amdgcn_mfma_f32_16x16x32_f16(af[kt], bfr[2][kt], a2, 0, 0, 0);
        }
        #pragma unroll
        for (int r = 0; r < 4; ++r) {
            float z0 = a0[r] + bf0;
            float z1 = a1[r] + bf1;
            float z2 = (r16 < 8) ? (a2[r] + bf2) : -INFINITY;
            float m = fmaxf(fmaxf(z0, z1), z2);
            #pragma unroll
            for (int o = 8; o; o >>= 1) m = fmaxf(m, __shfl_xor(m, o, 64));
            float s = expf(z0 - m) + expf(z1 - m) + ((r16 < 8) ? expf(z2 - m) : 0.f);
            #pragma unroll
            for (int o = 8; o; o >>= 1) s += __shfl_xor(s, o, 64);
            float ls = m + logf(s);
            int node = v0 + kg * 4 + r;
            if (node < N) {
                float* op = out + (size_t)node * 40;
                op[r16]      = z0 - ls;
                op[16 + r16] = z1 - ls;
                if (r16 < 8) op[32 + r16] = z2 - ls;
            }
        }
    }
}

extern "C" void kernel_launch(void* const* d_in, const int* in_sizes, int n_in,
                              void* d_out, int out_size, void* d_ws, size_t ws_size,
                              hipStream_t stream) {
    const float* x  = (const float*)d_in[0];
    const int*   ei = (const int*)d_in[1];   // [2, E]: row 0 = src, row 1 = dst
    const float* W1 = (const float*)d_in[2];
    const float* b1 = (const float*)d_in[3];
    const float* W2 = (const float*)d_in[4];
    const float* b2 = (const float*)d_in[5];
    const float* Wf = (const float*)d_in[6];
    const float* bf = (const float*)d_in[7];
    float* out = (float*)d_out;

    const int N = in_sizes[0] / 128;
    const int E = in_sizes[1] / 2;
    const int* src = ei;
    const int* dst = ei + E;
    const int NB = (N + 127) >> BSH;         // 128-node buckets (<=1024)

    auto align = [](size_t s) { return (s + 255) & ~(size_t)255; };
    char* ws = (char*)d_ws;
    size_t o = 0;
    int2*  rcp     = (int2*)(ws + o);  o += align((size_t)N * 8);
    float* dinv    = (float*)(ws + o); o += align((size_t)N * 4);
    int*   cursor1 = (int*)(ws + o);   o += align(1024 * 4);
    uint4* W1fr    = (uint4*)(ws + o); o += align(16 * 64 * 16);
    uint4* W2fr    = (uint4*)(ws + o); o += align(8 * 64 * 16);
    uint4* Wffr    = (uint4*)(ws + o); o += align(6 * 64 * 16);
    int*   csrc    = (int*)(ws + o);   o += align((size_t)NB * CAP * 4);
    unsigned int* B1 = (unsigned int*)(ws + o); o += align((size_t)N * 64);  // hs fp8
    float*  B2     = (float*)(ws + o);  o += align((size_t)N * 64 * 4);      // acc
    unsigned int* tmp = (unsigned int*)B2;   // alias: tmp dead before k_agg writes B2

    int blkT  = (E + T1 - 1) / T1;
    int ntile = (N + 15) / 16;
    int gX = 512;                     // persistent MFMA blocks (4 waves each)

    k_prep <<<1,   1024, 0, stream>>>(W1, W2, Wf, cursor1, W1fr, W2fr, Wffr, NB);
    k_pass1<<<blkT, 256, 0, stream>>>(src, dst, cursor1, tmp, E, NB);
    k_p2x  <<<NB,   512, 0, stream>>>(tmp, cursor1, rcp, csrc, dinv, x, W1fr, B1, N);

    int blkAgg = (N * 64 + 255) / 256;  // one wave per node
    k_agg   <<<blkAgg, 256, 0, stream>>>(rcp, csrc, B1, B2, N);
    k_xform2<<<gX, 256, 0, stream>>>(B2, W2fr, b1, dinv, B1, N, ntile);
    k_agg   <<<blkAgg, 256, 0, stream>>>(rcp, csrc, B1, B2, N);
    k_final <<<gX, 256, 0, stream>>>(B2, Wffr, b2, bf, dinv, out, N, ntile);
}

// Round 22
// 181.412 us; speedup vs baseline: 1.1383x; 1.0199x over previous
//
#include <hip/hip_runtime.h>
#include <hip/hip_fp16.h>
#include <cstdint>
#include <cstddef>
#include <cmath>

// ---------------------------------------------------------------------------
// GCN via CSR aggregation:
//   binning: fixed-capacity dst-buckets (128 nodes, CAP=6144); cursor counts
//            memset to 0 -> k_pass1 (512 thr, uint4 edge loads, two-level
//            scan) packs edges into tmp runs at i*CAP + reserved offset ->
//            k_p2x (512 thr): per-wave LDS histograms (uint4 stream) ->
//            2-wave shfl scan -> rcp/dinv -> per-wave cursor scatter ->
//            fused xform1 MFMA tail (1 tile/wave), W1 loaded directly.
//   agg: one wave per node, 4 lane-groups of 16, fp8 rows; unroll-8,
//        wave-uniform main loop (packed f32x2 adds) + single predicated tail.
//   xform2/final: MFMA 16x16x32 f16 persistent blocks (direct weight loads),
//   fp8 pack/unpack via v_cvt_pk_fp8_f32 / v_cvt_pk_f32_fp8
//   (byte b of uint s = channel s+16b). tmp aliases B2.
// ---------------------------------------------------------------------------

#define T1  4096    // edges per pass-1 tile
#define BSH 7       // 128-node buckets
#define CAP 6144    // bucket capacity (avg 4092, sigma ~64); divisible by 4

typedef _Float16 half8 __attribute__((ext_vector_type(8)));
typedef float f32x4 __attribute__((ext_vector_type(4)));
typedef float f32x2 __attribute__((ext_vector_type(2)));

// uint4 edge loads + two-level scan; cursor starts at 0, runs at i*CAP+off
__global__ __launch_bounds__(512) void k_pass1(const int* __restrict__ src,
        const int* __restrict__ dst, int* __restrict__ cursor1,
        unsigned int* __restrict__ tmp, int E, int NB) {
    __shared__ unsigned int pack[T1];                 // 16 KB
    __shared__ unsigned short bkt[T1];                //  8 KB
    __shared__ int h[1024], hs_[1024], gbase[1024];   // 12 KB
    __shared__ int wtot[8];
    int t = threadIdx.x;
    for (int i = t; i < 1024; i += 512) h[i] = 0;
    __syncthreads();
    int base = blockIdx.x * T1;
    int n = min(T1, E - base);
    int nv4 = n >> 2, rem = n & 3;
    unsigned int pk[8];
    int bl[8];
    #pragma unroll
    for (int i = 0; i < 2; ++i) {
        int g = i * 512 + t;                 // 4-edge group index
        if (g < nv4) {
            int4 s4 = ((const int4*)(src + base))[g];
            int4 d4 = ((const int4*)(dst + base))[g];
            int b0 = d4.x >> BSH;
            pk[4*i]   = (unsigned)s4.x | ((unsigned)(d4.x & 127) << 17);
            bl[4*i]   = (b0 << 13) | atomicAdd(&h[b0], 1);
            int b1 = d4.y >> BSH;
            pk[4*i+1] = (unsigned)s4.y | ((unsigned)(d4.y & 127) << 17);
            bl[4*i+1] = (b1 << 13) | atomicAdd(&h[b1], 1);
            int b2 = d4.z >> BSH;
            pk[4*i+2] = (unsigned)s4.z | ((unsigned)(d4.z & 127) << 17);
            bl[4*i+2] = (b2 << 13) | atomicAdd(&h[b2], 1);
            int b3 = d4.w >> BSH;
            pk[4*i+3] = (unsigned)s4.w | ((unsigned)(d4.w & 127) << 17);
            bl[4*i+3] = (b3 << 13) | atomicAdd(&h[b3], 1);
        } else {
            bl[4*i] = bl[4*i+1] = bl[4*i+2] = bl[4*i+3] = -1;
        }
    }
    unsigned int pk_r = 0; int bl_r = -1;     // scalar remainder (rem<4)
    if (t < rem) {
        int idx = nv4 * 4 + t;
        int s_ = src[base + idx], d = dst[base + idx];
        int b = d >> BSH;
        pk_r = (unsigned)s_ | ((unsigned)(d & 127) << 17);
        bl_r = (b << 13) | atomicAdd(&h[b], 1);
    }
    __syncthreads();
    // ---- two-level inclusive scan of h into hs_ ---------------------------
    {
        int b0 = 2 * t;
        int e0 = h[b0], e1 = h[b0 + 1];
        int sum2 = e0 + e1;
        int lane = t & 63, wv = t >> 6;
        int vv = sum2;
        #pragma unroll
        for (int o = 1; o < 64; o <<= 1) {
            int u = __shfl_up(vv, o, 64);
            if (lane >= o) vv += u;
        }
        if (lane == 63) wtot[wv] = vv;
        __syncthreads();
        int off = 0;
        #pragma unroll
        for (int w = 0; w < 8; ++w) off += (w < wv) ? wtot[w] : 0;
        int excl = off + vv - sum2;
        hs_[b0]     = excl + e0;
        hs_[b0 + 1] = excl + sum2;
    }
    __syncthreads();
    for (int i = t; i < NB; i += 512)
        gbase[i] = h[i] ? (i * CAP + atomicAdd(&cursor1[i], h[i])) : 0;
    __syncthreads();
    #pragma unroll
    for (int i = 0; i < 8; ++i) {
        if (bl[i] >= 0) {
            int b = bl[i] >> 13, lo = bl[i] & 8191;
            int slot = hs_[b] - h[b] + lo;
            pack[slot] = pk[i];
            bkt[slot]  = (unsigned short)b;
        }
    }
    if (bl_r >= 0) {
        int b = bl_r >> 13, lo = bl_r & 8191;
        int slot = hs_[b] - h[b] + lo;
        pack[slot] = pk_r;
        bkt[slot]  = (unsigned short)b;
    }
    __syncthreads();
    for (int s_ = t; s_ < n; s_ += 512) {
        int b = bkt[s_];
        tmp[gbase[b] + (s_ - (hs_[b] - h[b]))] = pack[s_];
    }
}

// per-bucket (128 nodes), 512 threads / 8 waves:
// per-wave uint4 histogram -> 2-wave shfl scan -> rcp/dinv ->
// per-wave cursor scatter -> fused xform1 MFMA tail (W1 direct).
__global__ __launch_bounds__(512) void k_p2x(const unsigned int* __restrict__ tmp,
        const int* __restrict__ cursor1, int2* __restrict__ rcp,
        int* __restrict__ csrc, float* __restrict__ dinv,
        const float* __restrict__ x, const float* __restrict__ W1,
        unsigned int* __restrict__ hs, int N) {
    __shared__ int c[8][128], cur[8][128];    // 8 KB
    __shared__ float sdinv[128];
    __shared__ int wsum;
    int t = threadIdx.x, b = blockIdx.x;
    int wv = t >> 6;
    for (int i = t; i < 1024; i += 512) ((int*)c)[i] = 0;
    __syncthreads();
    int s0 = b * CAP;
    int n = cursor1[b];
    int nv4 = n >> 2, rem = n & 3;
    const uint4* tmp4 = (const uint4*)(tmp + s0);
    for (int i = t; i < nv4; i += 512) {
        uint4 v = tmp4[i];
        atomicAdd(&c[wv][(v.x >> 17) & 127], 1);
        atomicAdd(&c[wv][(v.y >> 17) & 127], 1);
        atomicAdd(&c[wv][(v.z >> 17) & 127], 1);
        atomicAdd(&c[wv][(v.w >> 17) & 127], 1);
    }
    if (t < rem)
        atomicAdd(&c[wv][(tmp[s0 + nv4 * 4 + t] >> 17) & 127], 1);
    __syncthreads();
    int totv = 0, vv = 0;
    if (t < 128) {
        #pragma unroll
        for (int w = 0; w < 8; ++w) totv += c[w][t];
        vv = totv;
        #pragma unroll
        for (int o = 1; o < 64; o <<= 1) {
            int u = __shfl_up(vv, o, 64);
            if ((t & 63) >= o) vv += u;
        }
        if (t == 63) wsum = vv;
    }
    __syncthreads();
    if (t < 128) {
        if (t >= 64) vv += wsum;
        int rp = s0 + vv - totv;          // exclusive prefix
        float dv = rsqrtf((float)totv + 1.0f);   // +1 self loop
        sdinv[t] = dv;
        int node = b * 128 + t;
        if (node < N) {
            rcp[node]  = make_int2(rp, totv);
            dinv[node] = dv;
        }
        int run = rp;
        #pragma unroll
        for (int w = 0; w < 8; ++w) { cur[w][t] = run; run += c[w][t]; }
    }
    __syncthreads();
    for (int i = t; i < nv4; i += 512) {
        uint4 v = tmp4[i];
        int q0 = atomicAdd(&cur[wv][(v.x >> 17) & 127], 1);
        csrc[q0] = (int)(v.x & 0x1FFFFu);
        int q1 = atomicAdd(&cur[wv][(v.y >> 17) & 127], 1);
        csrc[q1] = (int)(v.y & 0x1FFFFu);
        int q2 = atomicAdd(&cur[wv][(v.z >> 17) & 127], 1);
        csrc[q2] = (int)(v.z & 0x1FFFFu);
        int q3 = atomicAdd(&cur[wv][(v.w >> 17) & 127], 1);
        csrc[q3] = (int)(v.w & 0x1FFFFu);
    }
    if (t < rem) {
        unsigned int p = tmp[s0 + nv4 * 4 + t];
        int q = atomicAdd(&cur[wv][(p >> 17) & 127], 1);
        csrc[q] = (int)(p & 0x1FFFFu);
    }
    __syncthreads();
    // ---------------- fused xform1 MFMA tail (1 tile per wave) ------------
    int lane = t & 63, wid = t >> 6;
    int r16 = lane & 15, kg = lane >> 4;
    half8 bf[4][4];                       // [coltile][ktile]
    #pragma unroll
    for (int ct = 0; ct < 4; ++ct)
        #pragma unroll
        for (int kt = 0; kt < 4; ++kt) {
            const float* wp = W1 + (kt * 32 + kg * 8) * 64 + ct * 16 + r16;
            half8 h;
            #pragma unroll
            for (int j = 0; j < 8; ++j) h[j] = (_Float16)wp[j * 64];
            bf[ct][kt] = h;
        }
    int v0 = b * 128 + wid * 16;
    int rowA = min(v0 + r16, N - 1);
    const float* xp = x + (size_t)rowA * 128 + kg * 8;
    half8 af[4];
    #pragma unroll
    for (int kt = 0; kt < 4; ++kt) {
        float4 p = *(const float4*)(xp + kt * 32);
        float4 q = *(const float4*)(xp + kt * 32 + 4);
        half8 a;
        a[0] = (_Float16)p.x; a[1] = (_Float16)p.y;
        a[2] = (_Float16)p.z; a[3] = (_Float16)p.w;
        a[4] = (_Float16)q.x; a[5] = (_Float16)q.y;
        a[6] = (_Float16)q.z; a[7] = (_Float16)q.w;
        af[kt] = a;
    }
    f32x4 acc0 = {0,0,0,0}, acc1 = {0,0,0,0}, acc2 = {0,0,0,0}, acc3 = {0,0,0,0};
    #pragma unroll
    for (int kt = 0; kt < 4; ++kt) {
        acc0 = __builtin_amdgcn_mfma_f32_16x16x32_f16(af[kt], bf[0][kt], acc0, 0, 0, 0);
        acc1 = __builtin_amdgcn_mfma_f32_16x16x32_f16(af[kt], bf[1][kt], acc1, 0, 0, 0);
        acc2 = __builtin_amdgcn_mfma_f32_16x16x32_f16(af[kt], bf[2][kt], acc2, 0, 0, 0);
        acc3 = __builtin_amdgcn_mfma_f32_16x16x32_f16(af[kt], bf[3][kt], acc3, 0, 0, 0);
    }
    #pragma unroll
    for (int r = 0; r < 4; ++r) {
        int nd = v0 + kg * 4 + r;
        if (nd < N) {
            float d = sdinv[wid * 16 + kg * 4 + r];
            int pk = __builtin_amdgcn_cvt_pk_fp8_f32(d * acc0[r], d * acc1[r], 0, false);
            pk     = __builtin_amdgcn_cvt_pk_fp8_f32(d * acc2[r], d * acc3[r], pk, true);
            hs[((size_t)nd << 4) + r16] = (unsigned int)pk;
        }
    }
}

// --- one wave per node, 4 lane-groups of 16; uniform main + masked tail ----
// fp8 row = 16 uints; byte b of uint s = channel s + 16*b.
__global__ __launch_bounds__(256) void k_agg(const int2* __restrict__ rcp,
        const int* __restrict__ csrc, const unsigned int* __restrict__ hp,
        float* __restrict__ acc, int N) {
    int w = (blockIdx.x * 256 + threadIdx.x) >> 6;
    int lane = threadIdx.x & 63;
    if (w >= N) return;
    int grp = lane >> 4, sub = lane & 15;
    int2 rc = rcp[w];
    int rs = rc.x, re = rc.x + rc.y;
    f32x2 A = {0.f, 0.f}, B = {0.f, 0.f};   // {sub, sub+16}, {sub+32, sub+48}
    if (grp == 0) {                                     // self loop, once
        unsigned v = hp[((size_t)w << 4) + sub];
        A = __builtin_amdgcn_cvt_pk_f32_fp8((int)v, false);
        B = __builtin_amdgcn_cvt_pk_f32_fp8((int)v, true);
    }
    int eb = rs;
    for (; eb + 32 <= re; eb += 32) {       // wave-uniform, no masks
        int e = eb + grp;
        int u0 = csrc[e];      int u1 = csrc[e + 4];
        int u2 = csrc[e + 8];  int u3 = csrc[e + 12];
        int u4 = csrc[e + 16]; int u5 = csrc[e + 20];
        int u6 = csrc[e + 24]; int u7 = csrc[e + 28];
        unsigned v0 = hp[((size_t)u0 << 4) + sub];
        unsigned v1 = hp[((size_t)u1 << 4) + sub];
        unsigned v2 = hp[((size_t)u2 << 4) + sub];
        unsigned v3 = hp[((size_t)u3 << 4) + sub];
        unsigned v4 = hp[((size_t)u4 << 4) + sub];
        unsigned v5 = hp[((size_t)u5 << 4) + sub];
        unsigned v6 = hp[((size_t)u6 << 4) + sub];
        unsigned v7 = hp[((size_t)u7 << 4) + sub];
        A += __builtin_amdgcn_cvt_pk_f32_fp8((int)v0, false);
        B += __builtin_amdgcn_cvt_pk_f32_fp8((int)v0, true);
        A += __builtin_amdgcn_cvt_pk_f32_fp8((int)v1, false);
        B += __builtin_amdgcn_cvt_pk_f32_fp8((int)v1, true);
        A += __builtin_amdgcn_cvt_pk_f32_fp8((int)v2, false);
        B += __builtin_amdgcn_cvt_pk_f32_fp8((int)v2, true);
        A += __builtin_amdgcn_cvt_pk_f32_fp8((int)v3, false);
        B += __builtin_amdgcn_cvt_pk_f32_fp8((int)v3, true);
        A += __builtin_amdgcn_cvt_pk_f32_fp8((int)v4, false);
        B += __builtin_amdgcn_cvt_pk_f32_fp8((int)v4, true);
        A += __builtin_amdgcn_cvt_pk_f32_fp8((int)v5, false);
        B += __builtin_amdgcn_cvt_pk_f32_fp8((int)v5, true);
        A += __builtin_amdgcn_cvt_pk_f32_fp8((int)v6, false);
        B += __builtin_amdgcn_cvt_pk_f32_fp8((int)v6, true);
        A += __builtin_amdgcn_cvt_pk_f32_fp8((int)v7, false);
        B += __builtin_amdgcn_cvt_pk_f32_fp8((int)v7, true);
    }
    int e = eb + grp;                       // masked tail, one iteration
    if (e < re) {
        int e1 = min(e + 4,  re - 1);
        int e2 = min(e + 8,  re - 1);
        int e3 = min(e + 12, re - 1);
        int e4 = min(e + 16, re - 1);
        int e5 = min(e + 20, re - 1);
        int e6 = min(e + 24, re - 1);
        int e7 = min(e + 28, re - 1);
        int u0 = csrc[e];
        int u1 = csrc[e1];
        int u2 = csrc[e2];
        int u3 = csrc[e3];
        int u4 = csrc[e4];
        int u5 = csrc[e5];
        int u6 = csrc[e6];
        int u7 = csrc[e7];
        unsigned v0 = hp[((size_t)u0 << 4) + sub];
        unsigned v1 = hp[((size_t)u1 << 4) + sub];
        unsigned v2 = hp[((size_t)u2 << 4) + sub];
        unsigned v3 = hp[((size_t)u3 << 4) + sub];
        unsigned v4 = hp[((size_t)u4 << 4) + sub];
        unsigned v5 = hp[((size_t)u5 << 4) + sub];
        unsigned v6 = hp[((size_t)u6 << 4) + sub];
        unsigned v7 = hp[((size_t)u7 << 4) + sub];
        float m1 = (e + 4  < re) ? 1.f : 0.f;
        float m2 = (e + 8  < re) ? 1.f : 0.f;
        float m3 = (e + 12 < re) ? 1.f : 0.f;
        float m4 = (e + 16 < re) ? 1.f : 0.f;
        float m5 = (e + 20 < re) ? 1.f : 0.f;
        float m6 = (e + 24 < re) ? 1.f : 0.f;
        float m7 = (e + 28 < re) ? 1.f : 0.f;
        A += __builtin_amdgcn_cvt_pk_f32_fp8((int)v0, false);
        B += __builtin_amdgcn_cvt_pk_f32_fp8((int)v0, true);
        f32x2 M1 = {m1, m1}, M2 = {m2, m2}, M3 = {m3, m3};
        f32x2 M4 = {m4, m4}, M5 = {m5, m5}, M6 = {m6, m6}, M7 = {m7, m7};
        A += M1 * __builtin_amdgcn_cvt_pk_f32_fp8((int)v1, false);
        B += M1 * __builtin_amdgcn_cvt_pk_f32_fp8((int)v1, true);
        A += M2 * __builtin_amdgcn_cvt_pk_f32_fp8((int)v2, false);
        B += M2 * __builtin_amdgcn_cvt_pk_f32_fp8((int)v2, true);
        A += M3 * __builtin_amdgcn_cvt_pk_f32_fp8((int)v3, false);
        B += M3 * __builtin_amdgcn_cvt_pk_f32_fp8((int)v3, true);
        A += M4 * __builtin_amdgcn_cvt_pk_f32_fp8((int)v4, false);
        B += M4 * __builtin_amdgcn_cvt_pk_f32_fp8((int)v4, true);
        A += M5 * __builtin_amdgcn_cvt_pk_f32_fp8((int)v5, false);
        B += M5 * __builtin_amdgcn_cvt_pk_f32_fp8((int)v5, true);
        A += M6 * __builtin_amdgcn_cvt_pk_f32_fp8((int)v6, false);
        B += M6 * __builtin_amdgcn_cvt_pk_f32_fp8((int)v6, true);
        A += M7 * __builtin_amdgcn_cvt_pk_f32_fp8((int)v7, false);
        B += M7 * __builtin_amdgcn_cvt_pk_f32_fp8((int)v7, true);
    }
    float a0 = A[0], a1 = A[1], a2 = B[0], a3 = B[1];
    a0 += __shfl_xor(a0, 16, 64); a0 += __shfl_xor(a0, 32, 64);
    a1 += __shfl_xor(a1, 16, 64); a1 += __shfl_xor(a1, 32, 64);
    a2 += __shfl_xor(a2, 16, 64); a2 += __shfl_xor(a2, 32, 64);
    a3 += __shfl_xor(a3, 16, 64); a3 += __shfl_xor(a3, 32, 64);
    if (grp == 0) {
        float* op = acc + ((size_t)w << 6) + sub;
        op[0]  = a0;
        op[16] = a1;
        op[32] = a2;
        op[48] = a3;
    }
}

// a = relu(dinv*acc + b1); hs2 = fp8(dinv * (a @ W2)) via MFMA; W2 direct
__global__ __launch_bounds__(256) void k_xform2(const float* __restrict__ acc_in,
        const float* __restrict__ W2, const float* __restrict__ b1,
        const float* __restrict__ dinv, unsigned int* __restrict__ hs2, int N, int ntiles) {
    int t = threadIdx.x;
    int lane = t & 63, wid = t >> 6;
    int r16 = lane & 15, kg = lane >> 4;
    half8 bf[4][2];
    #pragma unroll
    for (int ct = 0; ct < 4; ++ct)
        #pragma unroll
        for (int kt = 0; kt < 2; ++kt) {
            const float* wp = W2 + (kt * 32 + kg * 8) * 64 + ct * 16 + r16;
            half8 h;
            #pragma unroll
            for (int j = 0; j < 8; ++j) h[j] = (_Float16)wp[j * 64];
            bf[ct][kt] = h;
        }
    float b1r[2][8];
    #pragma unroll
    for (int kt = 0; kt < 2; ++kt)
        #pragma unroll
        for (int j = 0; j < 8; ++j) b1r[kt][j] = b1[kt * 32 + kg * 8 + j];
    int wtile = blockIdx.x * 4 + wid;
    int nw = gridDim.x * 4;
    for (int tile = wtile; tile < ntiles; tile += nw) {
        int v0 = tile * 16;
        int rowA = min(v0 + r16, N - 1);
        float da = dinv[rowA];
        const float* ap = acc_in + ((size_t)rowA << 6) + kg * 8;
        half8 af[2];
        #pragma unroll
        for (int kt = 0; kt < 2; ++kt) {
            float4 p = *(const float4*)(ap + kt * 32);
            float4 q = *(const float4*)(ap + kt * 32 + 4);
            half8 a;
            a[0] = (_Float16)fmaxf(fmaf(da, p.x, b1r[kt][0]), 0.f);
            a[1] = (_Float16)fmaxf(fmaf(da, p.y, b1r[kt][1]), 0.f);
            a[2] = (_Float16)fmaxf(fmaf(da, p.z, b1r[kt][2]), 0.f);
            a[3] = (_Float16)fmaxf(fmaf(da, p.w, b1r[kt][3]), 0.f);
            a[4] = (_Float16)fmaxf(fmaf(da, q.x, b1r[kt][4]), 0.f);
            a[5] = (_Float16)fmaxf(fmaf(da, q.y, b1r[kt][5]), 0.f);
            a[6] = (_Float16)fmaxf(fmaf(da, q.z, b1r[kt][6]), 0.f);
            a[7] = (_Float16)fmaxf(fmaf(da, q.w, b1r[kt][7]), 0.f);
            af[kt] = a;
        }
        f32x4 acc0 = {0,0,0,0}, acc1 = {0,0,0,0}, acc2 = {0,0,0,0}, acc3 = {0,0,0,0};
        #pragma unroll
        for (int kt = 0; kt < 2; ++kt) {
            acc0 = __builtin_amdgcn_mfma_f32_16x16x32_f16(af[kt], bf[0][kt], acc0, 0, 0, 0);
            acc1 = __builtin_amdgcn_mfma_f32_16x16x32_f16(af[kt], bf[1][kt], acc1, 0, 0, 0);
            acc2 = __builtin_amdgcn_mfma_f32_16x16x32_f16(af[kt], bf[2][kt], acc2, 0, 0, 0);
            acc3 = __builtin_amdgcn_mfma_f32_16x16x32_f16(af[kt], bf[3][kt], acc3, 0, 0, 0);
        }
        #pragma unroll
        for (int r = 0; r < 4; ++r) {
            int node = v0 + kg * 4 + r;
            if (node < N) {
                float d = dinv[node];
                int pk = __builtin_amdgcn_cvt_pk_fp8_f32(d * acc0[r], d * acc1[r], 0, false);
                pk     = __builtin_amdgcn_cvt_pk_fp8_f32(d * acc2[r], d * acc3[r], pk, true);
                hs2[((size_t)node << 4) + r16] = (unsigned int)pk;
            }
        }
    }
}

// a = relu(dinv*acc2 + b2); z = a @ Wf + bf; out = log_softmax(z); Wf direct
__global__ __launch_bounds__(256) void k_final(const float* __restrict__ acc2,
        const float* __restrict__ Wf, const float* __restrict__ b2,
        const float* __restrict__ bf, const float* __restrict__ dinv,
        float* __restrict__ out, int N, int ntiles) {
    int t = threadIdx.x;
    int lane = t & 63, wid = t >> 6;
    int r16 = lane & 15, kg = lane >> 4;
    half8 bfr[3][2];
    #pragma unroll
    for (int ct = 0; ct < 3; ++ct)
        #pragma unroll
        for (int kt = 0; kt < 2; ++kt) {
            int col = ct * 16 + r16;
            half8 h;
            #pragma unroll
            for (int j = 0; j < 8; ++j) {
                int k = kt * 32 + kg * 8 + j;
                h[j] = (col < 40) ? (_Float16)Wf[k * 40 + col] : (_Float16)0.f;
            }
            bfr[ct][kt] = h;
        }
    float b2r[2][8];
    #pragma unroll
    for (int kt = 0; kt < 2; ++kt)
        #pragma unroll
        for (int j = 0; j < 8; ++j) b2r[kt][j] = b2[kt * 32 + kg * 8 + j];
    float bf0 = bf[r16];
    float bf1 = bf[16 + r16];
    float bf2 = (r16 < 8) ? bf[32 + r16] : 0.f;
    int wtile = blockIdx.x * 4 + wid;
    int nw = gridDim.x * 4;
    for (int tile = wtile; tile < ntiles; tile += nw) {
        int v0 = tile * 16;
        int rowA = min(v0 + r16, N - 1);
        float da = dinv[rowA];
        const float* ap = acc2 + ((size_t)rowA << 6) + kg * 8;
        half8 af[2];
        #pragma unroll
        for (int kt = 0; kt < 2; ++kt) {
            float4 p = *(const float4*)(ap + kt * 32);
            float4 q = *(const float4*)(ap + kt * 32 + 4);
            half8 a;
            a[0] = (_Float16)fmaxf(fmaf(da, p.x, b2r[kt][0]), 0.f);
            a[1] = (_Float16)fmaxf(fmaf(da, p.y, b2r[kt][1]), 0.f);
            a[2] = (_Float16)fmaxf(fmaf(da, p.z, b2r[kt][2]), 0.f);
            a[3] = (_Float16)fmaxf(fmaf(da, p.w, b2r[kt][3]), 0.f);
            a[4] = (_Float16)fmaxf(fmaf(da, q.x, b2r[kt][4]), 0.f);
            a[5] = (_Float16)fmaxf(fmaf(da, q.y, b2r[kt][5]), 0.f);
            a[6] = (_Float16)fmaxf(fmaf(da, q.z, b2r[kt][6]), 0.f);
            a[7] = (_Float16)fmaxf(fmaf(da, q.w, b2r[kt][7]), 0.f);
            af[kt] = a;
        }
        f32x4 a0 = {0,0,0,0}, a1 = {0,0,0,0}, a2 = {0,0,0,0};
        #pragma unroll
        for (int kt = 0; kt < 2; ++kt) {
            a0 = __builtin_amdgcn_mfma_f32_16x16x32_f16(af[kt], bfr[0][kt], a0, 0, 0, 0);
            a1 = __builtin_amdgcn_mfma_f32_16x16x32_f16(af[kt], bfr[1][kt], a1, 0, 0, 0);
            a2 = __builtin_amdgcn_mfma_f32_16x16x32_f16(af[kt], bfr[2][kt], a2, 0, 0, 0);
        }
        #pragma unroll
        for (int r = 0; r < 4; ++r) {
            float z0 = a0[r] + bf0;
            float z1 = a1[r] + bf1;
            float z2 = (r16 < 8) ? (a2[r] + bf2) : -INFINITY;
            float m = fmaxf(fmaxf(z0, z1), z2);
            #pragma unroll
            for (int o = 8; o; o >>= 1) m = fmaxf(m, __shfl_xor(m, o, 64));
            float s = expf(z0 - m) + expf(z1 - m) + ((r16 < 8) ? expf(z2 - m) : 0.f);
            #pragma unroll
            for (int o = 8; o; o >>= 1) s += __shfl_xor(s, o, 64);
            float ls = m + logf(s);
            int node = v0 + kg * 4 + r;
            if (node < N) {
                float* op = out + (size_t)node * 40;
                op[r16]      = z0 - ls;
                op[16 + r16] = z1 - ls;
                if (r16 < 8) op[32 + r16] = z2 - ls;
            }
        }
    }
}

extern "C" void kernel_launch(void* const* d_in, const int* in_sizes, int n_in,
                              void* d_out, int out_size, void* d_ws, size_t ws_size,
                              hipStream_t stream) {
    const float* x  = (const float*)d_in[0];
    const int*   ei = (const int*)d_in[1];   // [2, E]: row 0 = src, row 1 = dst
    const float* W1 = (const float*)d_in[2];
    const float* b1 = (const float*)d_in[3];
    const float* W2 = (const float*)d_in[4];
    const float* b2 = (const float*)d_in[5];
    const float* Wf = (const float*)d_in[6];
    const float* bf = (const float*)d_in[7];
    float* out = (float*)d_out;

    const int N = in_sizes[0] / 128;
    const int E = in_sizes[1] / 2;
    const int* src = ei;
    const int* dst = ei + E;
    const int NB = (N + 127) >> BSH;         // 128-node buckets (<=1024)

    auto align = [](size_t s) { return (s + 255) & ~(size_t)255; };
    char* ws = (char*)d_ws;
    size_t o = 0;
    int2*  rcp     = (int2*)(ws + o);  o += align((size_t)N * 8);
    float* dinv    = (float*)(ws + o); o += align((size_t)N * 4);
    int*   cursor1 = (int*)(ws + o);   o += align(1024 * 4);
    int*   csrc    = (int*)(ws + o);   o += align((size_t)NB * CAP * 4);
    unsigned int* B1 = (unsigned int*)(ws + o); o += align((size_t)N * 64);  // hs fp8
    float*  B2     = (float*)(ws + o);  o += align((size_t)N * 64 * 4);      // acc
    unsigned int* tmp = (unsigned int*)B2;   // alias: tmp dead before k_agg writes B2

    hipMemsetAsync(cursor1, 0, (size_t)NB * 4, stream);

    int blkT  = (E + T1 - 1) / T1;
    int ntile = (N + 15) / 16;
    int gX = 512;                     // persistent MFMA blocks (4 waves each)

    k_pass1<<<blkT, 512, 0, stream>>>(src, dst, cursor1, tmp, E, NB);
    k_p2x  <<<NB,   512, 0, stream>>>(tmp, cursor1, rcp, csrc, dinv, x, W1, B1, N);

    int blkAgg = (N * 64 + 255) / 256;  // one wave per node
    k_agg   <<<blkAgg, 256, 0, stream>>>(rcp, csrc, B1, B2, N);
    k_xform2<<<gX, 256, 0, stream>>>(B2, W2, b1, dinv, B1, N, ntile);
    k_agg   <<<blkAgg, 256, 0, stream>>>(rcp, csrc, B1, B2, N);
    k_final <<<gX, 256, 0, stream>>>(B2, Wf, b2, bf, dinv, out, N, ntile);
}

// Round 23
// 177.291 us; speedup vs baseline: 1.1648x; 1.0232x over previous
//
#include <hip/hip_runtime.h>
#include <hip/hip_fp16.h>
#include <cstdint>
#include <cstddef>
#include <cmath>

// ---------------------------------------------------------------------------
// GCN via CSR aggregation:
//   binning: fixed-capacity dst-buckets (128 nodes, CAP=6144); cursor counts
//            memset to 0 -> k_pass1 (512 thr, uint4 edge loads, two-level
//            scan; block 0 also emits W1fr frag array) -> k_p2x (512 thr):
//            per-wave LDS histograms (uint4 stream) -> 2-wave shfl scan ->
//            rcp/dinv -> per-wave cursor scatter -> fused xform1 MFMA tail
//            reading W1fr coalesced.
//   agg: one wave per node, 4 lane-groups of 16, fp8 rows; unroll-8,
//        wave-uniform main loop (packed f32x2 adds) + single predicated tail.
//   xform2/final: MFMA 16x16x32 f16 persistent blocks (direct weight loads),
//   fp8 pack/unpack via v_cvt_pk_fp8_f32 / v_cvt_pk_f32_fp8
//   (byte b of uint s = channel s+16b). tmp aliases B2.
// ---------------------------------------------------------------------------

#define T1  4096    // edges per pass-1 tile
#define BSH 7       // 128-node buckets
#define CAP 6144    // bucket capacity (avg 4092, sigma ~64); divisible by 4

typedef _Float16 half8 __attribute__((ext_vector_type(8)));
typedef float f32x4 __attribute__((ext_vector_type(4)));
typedef float f32x2 __attribute__((ext_vector_type(2)));

// uint4 edge loads + two-level scan; cursor starts at 0, runs at i*CAP+off.
// Block 0, threads<64 additionally precompute W1 MFMA fragments into W1fr.
__global__ __launch_bounds__(512) void k_pass1(const int* __restrict__ src,
        const int* __restrict__ dst, int* __restrict__ cursor1,
        unsigned int* __restrict__ tmp, const float* __restrict__ W1,
        uint4* __restrict__ W1fr, int E, int NB) {
    __shared__ unsigned int pack[T1];                 // 16 KB
    __shared__ unsigned short bkt[T1];                //  8 KB
    __shared__ int h[1024], hs_[1024], gbase[1024];   // 12 KB
    __shared__ int wtot[8];
    int t = threadIdx.x;
    if (blockIdx.x == 0 && t < 64) {      // one-wave W1 frag precompute
        int r16 = t & 15, kg = t >> 4;
        #pragma unroll
        for (int ct = 0; ct < 4; ++ct)
            #pragma unroll
            for (int kt = 0; kt < 4; ++kt) {
                const float* wp = W1 + (kt * 32 + kg * 8) * 64 + ct * 16 + r16;
                half8 hh;
                #pragma unroll
                for (int j = 0; j < 8; ++j) hh[j] = (_Float16)wp[j * 64];
                W1fr[(ct * 4 + kt) * 64 + t] = *(uint4*)&hh;
            }
    }
    for (int i = t; i < 1024; i += 512) h[i] = 0;
    __syncthreads();
    int base = blockIdx.x * T1;
    int n = min(T1, E - base);
    int nv4 = n >> 2, rem = n & 3;
    unsigned int pk[8];
    int bl[8];
    #pragma unroll
    for (int i = 0; i < 2; ++i) {
        int g = i * 512 + t;                 // 4-edge group index
        if (g < nv4) {
            int4 s4 = ((const int4*)(src + base))[g];
            int4 d4 = ((const int4*)(dst + base))[g];
            int b0 = d4.x >> BSH;
            pk[4*i]   = (unsigned)s4.x | ((unsigned)(d4.x & 127) << 17);
            bl[4*i]   = (b0 << 13) | atomicAdd(&h[b0], 1);
            int b1 = d4.y >> BSH;
            pk[4*i+1] = (unsigned)s4.y | ((unsigned)(d4.y & 127) << 17);
            bl[4*i+1] = (b1 << 13) | atomicAdd(&h[b1], 1);
            int b2 = d4.z >> BSH;
            pk[4*i+2] = (unsigned)s4.z | ((unsigned)(d4.z & 127) << 17);
            bl[4*i+2] = (b2 << 13) | atomicAdd(&h[b2], 1);
            int b3 = d4.w >> BSH;
            pk[4*i+3] = (unsigned)s4.w | ((unsigned)(d4.w & 127) << 17);
            bl[4*i+3] = (b3 << 13) | atomicAdd(&h[b3], 1);
        } else {
            bl[4*i] = bl[4*i+1] = bl[4*i+2] = bl[4*i+3] = -1;
        }
    }
    unsigned int pk_r = 0; int bl_r = -1;     // scalar remainder (rem<4)
    if (t < rem) {
        int idx = nv4 * 4 + t;
        int s_ = src[base + idx], d = dst[base + idx];
        int b = d >> BSH;
        pk_r = (unsigned)s_ | ((unsigned)(d & 127) << 17);
        bl_r = (b << 13) | atomicAdd(&h[b], 1);
    }
    __syncthreads();
    // ---- two-level inclusive scan of h into hs_ ---------------------------
    {
        int b0 = 2 * t;
        int e0 = h[b0], e1 = h[b0 + 1];
        int sum2 = e0 + e1;
        int lane = t & 63, wv = t >> 6;
        int vv = sum2;
        #pragma unroll
        for (int o = 1; o < 64; o <<= 1) {
            int u = __shfl_up(vv, o, 64);
            if (lane >= o) vv += u;
        }
        if (lane == 63) wtot[wv] = vv;
        __syncthreads();
        int off = 0;
        #pragma unroll
        for (int w = 0; w < 8; ++w) off += (w < wv) ? wtot[w] : 0;
        int excl = off + vv - sum2;
        hs_[b0]     = excl + e0;
        hs_[b0 + 1] = excl + sum2;
    }
    __syncthreads();
    for (int i = t; i < NB; i += 512)
        gbase[i] = h[i] ? (i * CAP + atomicAdd(&cursor1[i], h[i])) : 0;
    __syncthreads();
    #pragma unroll
    for (int i = 0; i < 8; ++i) {
        if (bl[i] >= 0) {
            int b = bl[i] >> 13, lo = bl[i] & 8191;
            int slot = hs_[b] - h[b] + lo;
            pack[slot] = pk[i];
            bkt[slot]  = (unsigned short)b;
        }
    }
    if (bl_r >= 0) {
        int b = bl_r >> 13, lo = bl_r & 8191;
        int slot = hs_[b] - h[b] + lo;
        pack[slot] = pk_r;
        bkt[slot]  = (unsigned short)b;
    }
    __syncthreads();
    for (int s_ = t; s_ < n; s_ += 512) {
        int b = bkt[s_];
        tmp[gbase[b] + (s_ - (hs_[b] - h[b]))] = pack[s_];
    }
}

// per-bucket (128 nodes), 512 threads / 8 waves:
// per-wave uint4 histogram -> 2-wave shfl scan -> rcp/dinv ->
// per-wave cursor scatter -> fused xform1 MFMA tail (W1fr coalesced).
__global__ __launch_bounds__(512) void k_p2x(const unsigned int* __restrict__ tmp,
        const int* __restrict__ cursor1, int2* __restrict__ rcp,
        int* __restrict__ csrc, float* __restrict__ dinv,
        const float* __restrict__ x, const uint4* __restrict__ W1fr,
        unsigned int* __restrict__ hs, int N) {
    __shared__ int c[8][128], cur[8][128];    // 8 KB
    __shared__ float sdinv[128];
    __shared__ int wsum;
    int t = threadIdx.x, b = blockIdx.x;
    int wv = t >> 6;
    for (int i = t; i < 1024; i += 512) ((int*)c)[i] = 0;
    __syncthreads();
    int s0 = b * CAP;
    int n = cursor1[b];
    int nv4 = n >> 2, rem = n & 3;
    const uint4* tmp4 = (const uint4*)(tmp + s0);
    for (int i = t; i < nv4; i += 512) {
        uint4 v = tmp4[i];
        atomicAdd(&c[wv][(v.x >> 17) & 127], 1);
        atomicAdd(&c[wv][(v.y >> 17) & 127], 1);
        atomicAdd(&c[wv][(v.z >> 17) & 127], 1);
        atomicAdd(&c[wv][(v.w >> 17) & 127], 1);
    }
    if (t < rem)
        atomicAdd(&c[wv][(tmp[s0 + nv4 * 4 + t] >> 17) & 127], 1);
    __syncthreads();
    int totv = 0, vv = 0;
    if (t < 128) {
        #pragma unroll
        for (int w = 0; w < 8; ++w) totv += c[w][t];
        vv = totv;
        #pragma unroll
        for (int o = 1; o < 64; o <<= 1) {
            int u = __shfl_up(vv, o, 64);
            if ((t & 63) >= o) vv += u;
        }
        if (t == 63) wsum = vv;
    }
    __syncthreads();
    if (t < 128) {
        if (t >= 64) vv += wsum;
        int rp = s0 + vv - totv;          // exclusive prefix
        float dv = rsqrtf((float)totv + 1.0f);   // +1 self loop
        sdinv[t] = dv;
        int node = b * 128 + t;
        if (node < N) {
            rcp[node]  = make_int2(rp, totv);
            dinv[node] = dv;
        }
        int run = rp;
        #pragma unroll
        for (int w = 0; w < 8; ++w) { cur[w][t] = run; run += c[w][t]; }
    }
    __syncthreads();
    for (int i = t; i < nv4; i += 512) {
        uint4 v = tmp4[i];
        int q0 = atomicAdd(&cur[wv][(v.x >> 17) & 127], 1);
        csrc[q0] = (int)(v.x & 0x1FFFFu);
        int q1 = atomicAdd(&cur[wv][(v.y >> 17) & 127], 1);
        csrc[q1] = (int)(v.y & 0x1FFFFu);
        int q2 = atomicAdd(&cur[wv][(v.z >> 17) & 127], 1);
        csrc[q2] = (int)(v.z & 0x1FFFFu);
        int q3 = atomicAdd(&cur[wv][(v.w >> 17) & 127], 1);
        csrc[q3] = (int)(v.w & 0x1FFFFu);
    }
    if (t < rem) {
        unsigned int p = tmp[s0 + nv4 * 4 + t];
        int q = atomicAdd(&cur[wv][(p >> 17) & 127], 1);
        csrc[q] = (int)(p & 0x1FFFFu);
    }
    __syncthreads();
    // ---------------- fused xform1 MFMA tail (1 tile per wave) ------------
    int lane = t & 63, wid = t >> 6;
    int r16 = lane & 15, kg = lane >> 4;
    half8 bf[4][4];                       // [coltile][ktile]
    #pragma unroll
    for (int ct = 0; ct < 4; ++ct)
        #pragma unroll
        for (int kt = 0; kt < 4; ++kt)
            bf[ct][kt] = *(const half8*)&W1fr[(ct * 4 + kt) * 64 + lane];
    int v0 = b * 128 + wid * 16;
    int rowA = min(v0 + r16, N - 1);
    const float* xp = x + (size_t)rowA * 128 + kg * 8;
    half8 af[4];
    #pragma unroll
    for (int kt = 0; kt < 4; ++kt) {
        float4 p = *(const float4*)(xp + kt * 32);
        float4 q = *(const float4*)(xp + kt * 32 + 4);
        half8 a;
        a[0] = (_Float16)p.x; a[1] = (_Float16)p.y;
        a[2] = (_Float16)p.z; a[3] = (_Float16)p.w;
        a[4] = (_Float16)q.x; a[5] = (_Float16)q.y;
        a[6] = (_Float16)q.z; a[7] = (_Float16)q.w;
        af[kt] = a;
    }
    f32x4 acc0 = {0,0,0,0}, acc1 = {0,0,0,0}, acc2 = {0,0,0,0}, acc3 = {0,0,0,0};
    #pragma unroll
    for (int kt = 0; kt < 4; ++kt) {
        acc0 = __builtin_amdgcn_mfma_f32_16x16x32_f16(af[kt], bf[0][kt], acc0, 0, 0, 0);
        acc1 = __builtin_amdgcn_mfma_f32_16x16x32_f16(af[kt], bf[1][kt], acc1, 0, 0, 0);
        acc2 = __builtin_amdgcn_mfma_f32_16x16x32_f16(af[kt], bf[2][kt], acc2, 0, 0, 0);
        acc3 = __builtin_amdgcn_mfma_f32_16x16x32_f16(af[kt], bf[3][kt], acc3, 0, 0, 0);
    }
    #pragma unroll
    for (int r = 0; r < 4; ++r) {
        int nd = v0 + kg * 4 + r;
        if (nd < N) {
            float d = sdinv[wid * 16 + kg * 4 + r];
            int pk = __builtin_amdgcn_cvt_pk_fp8_f32(d * acc0[r], d * acc1[r], 0, false);
            pk     = __builtin_amdgcn_cvt_pk_fp8_f32(d * acc2[r], d * acc3[r], pk, true);
            hs[((size_t)nd << 4) + r16] = (unsigned int)pk;
        }
    }
}

// --- one wave per node, 4 lane-groups of 16; uniform main + masked tail ----
// fp8 row = 16 uints; byte b of uint s = channel s + 16*b.
__global__ __launch_bounds__(256) void k_agg(const int2* __restrict__ rcp,
        const int* __restrict__ csrc, const unsigned int* __restrict__ hp,
        float* __restrict__ acc, int N) {
    int w = (blockIdx.x * 256 + threadIdx.x) >> 6;
    int lane = threadIdx.x & 63;
    if (w >= N) return;
    int grp = lane >> 4, sub = lane & 15;
    int2 rc = rcp[w];
    int rs = rc.x, re = rc.x + rc.y;
    f32x2 A = {0.f, 0.f}, B = {0.f, 0.f};   // {sub, sub+16}, {sub+32, sub+48}
    if (grp == 0) {                                     // self loop, once
        unsigned v = hp[((size_t)w << 4) + sub];
        A = __builtin_amdgcn_cvt_pk_f32_fp8((int)v, false);
        B = __builtin_amdgcn_cvt_pk_f32_fp8((int)v, true);
    }
    int eb = rs;
    for (; eb + 32 <= re; eb += 32) {       // wave-uniform, no masks
        int e = eb + grp;
        int u0 = csrc[e];      int u1 = csrc[e + 4];
        int u2 = csrc[e + 8];  int u3 = csrc[e + 12];
        int u4 = csrc[e + 16]; int u5 = csrc[e + 20];
        int u6 = csrc[e + 24]; int u7 = csrc[e + 28];
        unsigned v0 = hp[((size_t)u0 << 4) + sub];
        unsigned v1 = hp[((size_t)u1 << 4) + sub];
        unsigned v2 = hp[((size_t)u2 << 4) + sub];
        unsigned v3 = hp[((size_t)u3 << 4) + sub];
        unsigned v4 = hp[((size_t)u4 << 4) + sub];
        unsigned v5 = hp[((size_t)u5 << 4) + sub];
        unsigned v6 = hp[((size_t)u6 << 4) + sub];
        unsigned v7 = hp[((size_t)u7 << 4) + sub];
        A += __builtin_amdgcn_cvt_pk_f32_fp8((int)v0, false);
        B += __builtin_amdgcn_cvt_pk_f32_fp8((int)v0, true);
        A += __builtin_amdgcn_cvt_pk_f32_fp8((int)v1, false);
        B += __builtin_amdgcn_cvt_pk_f32_fp8((int)v1, true);
        A += __builtin_amdgcn_cvt_pk_f32_fp8((int)v2, false);
        B += __builtin_amdgcn_cvt_pk_f32_fp8((int)v2, true);
        A += __builtin_amdgcn_cvt_pk_f32_fp8((int)v3, false);
        B += __builtin_amdgcn_cvt_pk_f32_fp8((int)v3, true);
        A += __builtin_amdgcn_cvt_pk_f32_fp8((int)v4, false);
        B += __builtin_amdgcn_cvt_pk_f32_fp8((int)v4, true);
        A += __builtin_amdgcn_cvt_pk_f32_fp8((int)v5, false);
        B += __builtin_amdgcn_cvt_pk_f32_fp8((int)v5, true);
        A += __builtin_amdgcn_cvt_pk_f32_fp8((int)v6, false);
        B += __builtin_amdgcn_cvt_pk_f32_fp8((int)v6, true);
        A += __builtin_amdgcn_cvt_pk_f32_fp8((int)v7, false);
        B += __builtin_amdgcn_cvt_pk_f32_fp8((int)v7, true);
    }
    int e = eb + grp;                       // masked tail, one iteration
    if (e < re) {
        int e1 = min(e + 4,  re - 1);
        int e2 = min(e + 8,  re - 1);
        int e3 = min(e + 12, re - 1);
        int e4 = min(e + 16, re - 1);
        int e5 = min(e + 20, re - 1);
        int e6 = min(e + 24, re - 1);
        int e7 = min(e + 28, re - 1);
        int u0 = csrc[e];
        int u1 = csrc[e1];
        int u2 = csrc[e2];
        int u3 = csrc[e3];
        int u4 = csrc[e4];
        int u5 = csrc[e5];
        int u6 = csrc[e6];
        int u7 = csrc[e7];
        unsigned v0 = hp[((size_t)u0 << 4) + sub];
        unsigned v1 = hp[((size_t)u1 << 4) + sub];
        unsigned v2 = hp[((size_t)u2 << 4) + sub];
        unsigned v3 = hp[((size_t)u3 << 4) + sub];
        unsigned v4 = hp[((size_t)u4 << 4) + sub];
        unsigned v5 = hp[((size_t)u5 << 4) + sub];
        unsigned v6 = hp[((size_t)u6 << 4) + sub];
        unsigned v7 = hp[((size_t)u7 << 4) + sub];
        float m1 = (e + 4  < re) ? 1.f : 0.f;
        float m2 = (e + 8  < re) ? 1.f : 0.f;
        float m3 = (e + 12 < re) ? 1.f : 0.f;
        float m4 = (e + 16 < re) ? 1.f : 0.f;
        float m5 = (e + 20 < re) ? 1.f : 0.f;
        float m6 = (e + 24 < re) ? 1.f : 0.f;
        float m7 = (e + 28 < re) ? 1.f : 0.f;
        A += __builtin_amdgcn_cvt_pk_f32_fp8((int)v0, false);
        B += __builtin_amdgcn_cvt_pk_f32_fp8((int)v0, true);
        f32x2 M1 = {m1, m1}, M2 = {m2, m2}, M3 = {m3, m3};
        f32x2 M4 = {m4, m4}, M5 = {m5, m5}, M6 = {m6, m6}, M7 = {m7, m7};
        A += M1 * __builtin_amdgcn_cvt_pk_f32_fp8((int)v1, false);
        B += M1 * __builtin_amdgcn_cvt_pk_f32_fp8((int)v1, true);
        A += M2 * __builtin_amdgcn_cvt_pk_f32_fp8((int)v2, false);
        B += M2 * __builtin_amdgcn_cvt_pk_f32_fp8((int)v2, true);
        A += M3 * __builtin_amdgcn_cvt_pk_f32_fp8((int)v3, false);
        B += M3 * __builtin_amdgcn_cvt_pk_f32_fp8((int)v3, true);
        A += M4 * __builtin_amdgcn_cvt_pk_f32_fp8((int)v4, false);
        B += M4 * __builtin_amdgcn_cvt_pk_f32_fp8((int)v4, true);
        A += M5 * __builtin_amdgcn_cvt_pk_f32_fp8((int)v5, false);
        B += M5 * __builtin_amdgcn_cvt_pk_f32_fp8((int)v5, true);
        A += M6 * __builtin_amdgcn_cvt_pk_f32_fp8((int)v6, false);
        B += M6 * __builtin_amdgcn_cvt_pk_f32_fp8((int)v6, true);
        A += M7 * __builtin_amdgcn_cvt_pk_f32_fp8((int)v7, false);
        B += M7 * __builtin_amdgcn_cvt_pk_f32_fp8((int)v7, true);
    }
    float a0 = A[0], a1 = A[1], a2 = B[0], a3 = B[1];
    a0 += __shfl_xor(a0, 16, 64); a0 += __shfl_xor(a0, 32, 64);
    a1 += __shfl_xor(a1, 16, 64); a1 += __shfl_xor(a1, 32, 64);
    a2 += __shfl_xor(a2, 16, 64); a2 += __shfl_xor(a2, 32, 64);
    a3 += __shfl_xor(a3, 16, 64); a3 += __shfl_xor(a3, 32, 64);
    if (grp == 0) {
        float* op = acc + ((size_t)w << 6) + sub;
        op[0]  = a0;
        op[16] = a1;
        op[32] = a2;
        op[48] = a3;
    }
}

// a = relu(dinv*acc + b1); hs2 = fp8(dinv * (a @ W2)) via MFMA; W2 direct
__global__ __launch_bounds__(256) void k_xform2(const float* __restrict__ acc_in,
        const float* __restrict__ W2, const float* __restrict__ b1,
        const float* __restrict__ dinv, unsigned int* __restrict__ hs2, int N, int ntiles) {
    int t = threadIdx.x;
    int lane = t & 63, wid = t >> 6;
    int r16 = lane & 15, kg = lane >> 4;
    half8 bf[4][2];
    #pragma unroll
    for (int ct = 0; ct < 4; ++ct)
        #pragma unroll
        for (int kt = 0; kt < 2; ++kt) {
            const float* wp = W2 + (kt * 32 + kg * 8) * 64 + ct * 16 + r16;
            half8 h;
            #pragma unroll
            for (int j = 0; j < 8; ++j) h[j] = (_Float16)wp[j * 64];
            bf[ct][kt] = h;
        }
    float b1r[2][8];
    #pragma unroll
    for (int kt = 0; kt < 2; ++kt)
        #pragma unroll
        for (int j = 0; j < 8; ++j) b1r[kt][j] = b1[kt * 32 + kg * 8 + j];
    int wtile = blockIdx.x * 4 + wid;
    int nw = gridDim.x * 4;
    for (int tile = wtile; tile < ntiles; tile += nw) {
        int v0 = tile * 16;
        int rowA = min(v0 + r16, N - 1);
        float da = dinv[rowA];
        const float* ap = acc_in + ((size_t)rowA << 6) + kg * 8;
        half8 af[2];
        #pragma unroll
        for (int kt = 0; kt < 2; ++kt) {
            float4 p = *(const float4*)(ap + kt * 32);
            float4 q = *(const float4*)(ap + kt * 32 + 4);
            half8 a;
            a[0] = (_Float16)fmaxf(fmaf(da, p.x, b1r[kt][0]), 0.f);
            a[1] = (_Float16)fmaxf(fmaf(da, p.y, b1r[kt][1]), 0.f);
            a[2] = (_Float16)fmaxf(fmaf(da, p.z, b1r[kt][2]), 0.f);
            a[3] = (_Float16)fmaxf(fmaf(da, p.w, b1r[kt][3]), 0.f);
            a[4] = (_Float16)fmaxf(fmaf(da, q.x, b1r[kt][4]), 0.f);
            a[5] = (_Float16)fmaxf(fmaf(da, q.y, b1r[kt][5]), 0.f);
            a[6] = (_Float16)fmaxf(fmaf(da, q.z, b1r[kt][6]), 0.f);
            a[7] = (_Float16)fmaxf(fmaf(da, q.w, b1r[kt][7]), 0.f);
            af[kt] = a;
        }
        f32x4 acc0 = {0,0,0,0}, acc1 = {0,0,0,0}, acc2 = {0,0,0,0}, acc3 = {0,0,0,0};
        #pragma unroll
        for (int kt = 0; kt < 2; ++kt) {
            acc0 = __builtin_amdgcn_mfma_f32_16x16x32_f16(af[kt], bf[0][kt], acc0, 0, 0, 0);
            acc1 = __builtin_amdgcn_mfma_f32_16x16x32_f16(af[kt], bf[1][kt], acc1, 0, 0, 0);
            acc2 = __builtin_amdgcn_mfma_f32_16x16x32_f16(af[kt], bf[2][kt], acc2, 0, 0, 0);
            acc3 = __builtin_amdgcn_mfma_f32_16x16x32_f16(af[kt], bf[3][kt], acc3, 0, 0, 0);
        }
        #pragma unroll
        for (int r = 0; r < 4; ++r) {
            int node = v0 + kg * 4 + r;
            if (node < N) {
                float d = dinv[node];
                int pk = __builtin_amdgcn_cvt_pk_fp8_f32(d * acc0[r], d * acc1[r], 0, false);
                pk     = __builtin_amdgcn_cvt_pk_fp8_f32(d * acc2[r], d * acc3[r], pk, true);
                hs2[((size_t)node << 4) + r16] = (unsigned int)pk;
            }
        }
    }
}

// a = relu(dinv*acc2 + b2); z = a @ Wf + bf; out = log_softmax(z); Wf direct
__global__ __launch_bounds__(256) void k_final(const float* __restrict__ acc2,
        const float* __restrict__ Wf, const float* __restrict__ b2,
        const float* __restrict__ bf, const float* __restrict__ dinv,
        float* __restrict__ out, int N, int ntiles) {
    int t = threadIdx.x;
    int lane = t & 63, wid = t >> 6;
    int r16 = lane & 15, kg = lane >> 4;
    half8 bfr[3][2];
    #pragma unroll
    for (int ct = 0; ct < 3; ++ct)
        #pragma unroll
        for (int kt = 0; kt < 2; ++kt) {
            int col = ct * 16 + r16;
            half8 h;
            #pragma unroll
            for (int j = 0; j < 8; ++j) {
                int k = kt * 32 + kg * 8 + j;
                h[j] = (col < 40) ? (_Float16)Wf[k * 40 + col] : (_Float16)0.f;
            }
            bfr[ct][kt] = h;
        }
    float b2r[2][8];
    #pragma unroll
    for (int kt = 0; kt < 2; ++kt)
        #pragma unroll
        for (int j = 0; j < 8; ++j) b2r[kt][j] = b2[kt * 32 + kg * 8 + j];
    float bf0 = bf[r16];
    float bf1 = bf[16 + r16];
    float bf2 = (r16 < 8) ? bf[32 + r16] : 0.f;
    int wtile = blockIdx.x * 4 + wid;
    int nw = gridDim.x * 4;
    for (int tile = wtile; tile < ntiles; tile += nw) {
        int v0 = tile * 16;
        int rowA = min(v0 + r16, N - 1);
        float da = dinv[rowA];
        const float* ap = acc2 + ((size_t)rowA << 6) + kg * 8;
        half8 af[2];
        #pragma unroll
        for (int kt = 0; kt < 2; ++kt) {
            float4 p = *(const float4*)(ap + kt * 32);
            float4 q = *(const float4*)(ap + kt * 32 + 4);
            half8 a;
            a[0] = (_Float16)fmaxf(fmaf(da, p.x, b2r[kt][0]), 0.f);
            a[1] = (_Float16)fmaxf(fmaf(da, p.y, b2r[kt][1]), 0.f);
            a[2] = (_Float16)fmaxf(fmaf(da, p.z, b2r[kt][2]), 0.f);
            a[3] = (_Float16)fmaxf(fmaf(da, p.w, b2r[kt][3]), 0.f);
            a[4] = (_Float16)fmaxf(fmaf(da, q.x, b2r[kt][4]), 0.f);
            a[5] = (_Float16)fmaxf(fmaf(da, q.y, b2r[kt][5]), 0.f);
            a[6] = (_Float16)fmaxf(fmaf(da, q.z, b2r[kt][6]), 0.f);
            a[7] = (_Float16)fmaxf(fmaf(da, q.w, b2r[kt][7]), 0.f);
            af[kt] = a;
        }
        f32x4 a0 = {0,0,0,0}, a1 = {0,0,0,0}, a2 = {0,0,0,0};
        #pragma unroll
        for (int kt = 0; kt < 2; ++kt) {
            a0 = __builtin_amdgcn_mfma_f32_16x16x32_f16(af[kt], bfr[0][kt], a0, 0, 0, 0);
            a1 = __builtin_amdgcn_mfma_f32_16x16x32_f16(af[kt], bfr[1][kt], a1, 0, 0, 0);
            a2 = __builtin_amdgcn_mfma_f32_16x16x32_f16(af[kt], bfr[2][kt], a2, 0, 0, 0);
        }
        #pragma unroll
        for (int r = 0; r < 4; ++r) {
            float z0 = a0[r] + bf0;
            float z1 = a1[r] + bf1;
            float z2 = (r16 < 8) ? (a2[r] + bf2) : -INFINITY;
            float m = fmaxf(fmaxf(z0, z1), z2);
            #pragma unroll
            for (int o = 8; o; o >>= 1) m = fmaxf(m, __shfl_xor(m, o, 64));
            float s = expf(z0 - m) + expf(z1 - m) + ((r16 < 8) ? expf(z2 - m) : 0.f);
            #pragma unroll
            for (int o = 8; o; o >>= 1) s += __shfl_xor(s, o, 64);
            float ls = m + logf(s);
            int node = v0 + kg * 4 + r;
            if (node < N) {
                float* op = out + (size_t)node * 40;
                op[r16]      = z0 - ls;
                op[16 + r16] = z1 - ls;
                if (r16 < 8) op[32 + r16] = z2 - ls;
            }
        }
    }
}

extern "C" void kernel_launch(void* const* d_in, const int* in_sizes, int n_in,
                              void* d_out, int out_size, void* d_ws, size_t ws_size,
                              hipStream_t stream) {
    const float* x  = (const float*)d_in[0];
    const int*   ei = (const int*)d_in[1];   // [2, E]: row 0 = src, row 1 = dst
    const float* W1 = (const float*)d_in[2];
    const float* b1 = (const float*)d_in[3];
    const float* W2 = (const float*)d_in[4];
    const float* b2 = (const float*)d_in[5];
    const float* Wf = (const float*)d_in[6];
    const float* bf = (const float*)d_in[7];
    float* out = (float*)d_out;

    const int N = in_sizes[0] / 128;
    const int E = in_sizes[1] / 2;
    const int* src = ei;
    const int* dst = ei + E;
    const int NB = (N + 127) >> BSH;         // 128-node buckets (<=1024)

    auto align = [](size_t s) { return (s + 255) & ~(size_t)255; };
    char* ws = (char*)d_ws;
    size_t o = 0;
    int2*  rcp     = (int2*)(ws + o);  o += align((size_t)N * 8);
    float* dinv    = (float*)(ws + o); o += align((size_t)N * 4);
    int*   cursor1 = (int*)(ws + o);   o += align(1024 * 4);
    uint4* W1fr    = (uint4*)(ws + o); o += align(16 * 64 * 16);
    int*   csrc    = (int*)(ws + o);   o += align((size_t)NB * CAP * 4);
    unsigned int* B1 = (unsigned int*)(ws + o); o += align((size_t)N * 64);  // hs fp8
    float*  B2     = (float*)(ws + o);  o += align((size_t)N * 64 * 4);      // acc
    unsigned int* tmp = (unsigned int*)B2;   // alias: tmp dead before k_agg writes B2

    hipMemsetAsync(cursor1, 0, (size_t)NB * 4, stream);

    int blkT  = (E + T1 - 1) / T1;
    int ntile = (N + 15) / 16;
    int gX = 1024;                    // persistent MFMA blocks (4 waves each)

    k_pass1<<<blkT, 512, 0, stream>>>(src, dst, cursor1, tmp, W1, W1fr, E, NB);
    k_p2x  <<<NB,   512, 0, stream>>>(tmp, cursor1, rcp, csrc, dinv, x, W1fr, B1, N);

    int blkAgg = (N * 64 + 255) / 256;  // one wave per node
    k_agg   <<<blkAgg, 256, 0, stream>>>(rcp, csrc, B1, B2, N);
    k_xform2<<<gX, 256, 0, stream>>>(B2, W2, b1, dinv, B1, N, ntile);
    k_agg   <<<blkAgg, 256, 0, stream>>>(rcp, csrc, B1, B2, N);
    k_final <<<gX, 256, 0, stream>>>(B2, Wf, b2, bf, dinv, out, N, ntile);
}